// Round 13
// baseline (321.892 us; speedup 1.0000x reference)
//
#include <hip/hip_runtime.h>
#include <hip/hip_bf16.h>
#include <stdint.h>
#include <stddef.h>

// Problem constants (fixed by the reference)
#define BB 2
#define NSEQ 2048
#define DM 1024
#define H 16
#define HD 128
#define D1 2048
#define NKI 16
#define RANKI 32
#define MROWS (BB * NSEQ)   // 4096 rows for all GEMMs
#define VPROWS 6144         // 2048 zero-pad | 2048 data | 2048 zero-pad
#define NTAP 28
#define NPAIR 13
#define NCHUNK 128
#define CLEN 16
#define GAMMA_F 0.999f
#define G_CL 0.9841201f     // 0.999^16 (chunk-length homogeneous decay)
// ln(0.999), for gamma^x = exp(x*ln_g)  (__exp2f collides with glibc; __expf is safe)
#define LN_G (-1.00050033e-3f)

// NOTE: delta must remain fp32 everywhere — h[tau] = (tau+1)g^tau amplifies
// delta errors by up to ~368 [R9]. Do NOT XOR-swizzle gemm LDS [R10/R11].
__device__ constexpr int TAPS[NTAP] = {
  1, 2, 138, 139, 274, 275, 411, 412, 547, 548, 684,
  820, 821, 956, 957, 1093, 1094, 1229, 1230, 1366,
  1502, 1503, 1638, 1639, 1775, 1776, 1911, 1912};
__device__ constexpr int LEADL[NPAIR] = {1, 138, 274, 411, 547, 820, 956, 1093, 1229, 1502, 1638, 1775, 1911};
__device__ constexpr int LEADI[NPAIR] = {0, 2, 4, 6, 8, 11, 13, 15, 17, 20, 22, 24, 26};
#define SGL0_L 684
#define SGL0_I 10
#define SGL1_L 1366
#define SGL1_I 19

typedef short short8 __attribute__((ext_vector_type(8)));
typedef float floatx16 __attribute__((ext_vector_type(16)));

__device__ __forceinline__ float bf2f(unsigned short u) {
  union { unsigned int i; float f; } v; v.i = ((unsigned int)u) << 16; return v.f;
}
__device__ __forceinline__ unsigned short f2bf(float f) {
  union { float f; unsigned int i; } v; v.f = f;
  unsigned int r = (v.i + 0x7FFFu + ((v.i >> 16) & 1u)) >> 16;
  return (unsigned short)r;
}
__device__ __forceinline__ float bflo(unsigned int p) {
  union { unsigned int i; float f; } v; v.i = p << 16; return v.f;
}
__device__ __forceinline__ float bfhi(unsigned int p) {
  union { unsigned int i; float f; } v; v.i = p & 0xffff0000u; return v.f;
}
// async 16B global->LDS DMA: lane i lands at (wave-uniform) l + i*16 bytes
__device__ __forceinline__ void async16(const unsigned short* g, unsigned short* l) {
  __builtin_amdgcn_global_load_lds(
      (const __attribute__((address_space(1))) unsigned int*)g,
      (__attribute__((address_space(3))) unsigned int*)l, 16, 0, 0);
}

// ------- prep: x fp32->bf16 convert + zero the 4 V pad regions (1 dispatch) -
#define CVT4 (MROWS * DM / 4)            // 1048576 float4->ushort4 units
#define PAD16 (4 * NSEQ * D1 / 8)        // 2097152 uint4 (8-short) pad writes
__global__ __launch_bounds__(256) void prep_kernel(const float* __restrict__ x,
                                                   unsigned short* __restrict__ x_bf,
                                                   unsigned short* __restrict__ Vp) {
  int i = blockIdx.x * 256 + threadIdx.x;
  if (i < CVT4) {
    float4 f = ((const float4*)x)[i];
    ushort4 o;
    o.x = f2bf(f.x); o.y = f2bf(f.y); o.z = f2bf(f.z); o.w = f2bf(f.w);
    ((ushort4*)x_bf)[i] = o;
  } else {
    int j = i - CVT4;
    if (j < PAD16) {
      int r = j >> 19;            // region 0..3, each 524288 uint4
      int off = j & 524287;
      const size_t bases[4] = {0, (size_t)4096 * D1, (size_t)VPROWS * D1,
                               (size_t)VPROWS * D1 + (size_t)4096 * D1};
      uint4 z; z.x = z.y = z.z = z.w = 0u;
      ((uint4*)(Vp + bases[r]))[off] = z;
    }
  }
}

// ------- fused transpose+convert: out_bf16[c][r] = in_f32[r][c] ------------
__global__ __launch_bounds__(256) void tpc_kernel(const float* __restrict__ inA,
                                                  unsigned short* __restrict__ outA,
                                                  const float* __restrict__ inB,
                                                  unsigned short* __restrict__ outB,
                                                  int rows, int cols) {
  __shared__ unsigned short t[32][33];
  const float* in = blockIdx.z ? inB : inA;
  unsigned short* out = blockIdx.z ? outB : outA;
  int bx = blockIdx.x * 32, by = blockIdx.y * 32;
  int tx = threadIdx.x, ty = threadIdx.y; // blockDim = (32,8)
#pragma unroll
  for (int j = 0; j < 32; j += 8)
    t[ty + j][tx] = f2bf(in[(size_t)(by + ty + j) * cols + bx + tx]);
  __syncthreads();
#pragma unroll
  for (int j = 0; j < 32; j += 8)
    out[(size_t)(bx + ty + j) * rows + by + tx] = t[tx][ty + j];
}

// ---- K(l) = interp(kind, l) * gamma^l on an LDS copy of kind --------------
__device__ __forceinline__ float KinterpL(const float* kk, int l, int d) {
  if (l < 1) return 0.0f;   // l > 2047 never queried (max tap 1912)
  float p = (float)(l - 1) * (15.0f / 2046.0f);
  int lo = (int)p; if (lo > 15) lo = 15;
  int hi = lo + 1; if (hi > 15) hi = 15;
  float w = p - (float)lo;
  float v = kk[lo * HD + d] * (1.0f - w) + kk[hi * HD + d] * w;
  return v * __powf(GAMMA_F, (float)l);
}

// ---- fused: kind = a@b per (head,dir) -> fp32 delta table at taps ---------
__global__ __launch_bounds__(256) void kdtab_kernel(const float* __restrict__ ap,
                                                    const float* __restrict__ bp,
                                                    const float* __restrict__ an,
                                                    const float* __restrict__ bn,
                                                    float* __restrict__ dtp,
                                                    float* __restrict__ dtn) {
  __shared__ float kk[NKI * HD];  // 8 KB
  int h = blockIdx.x, dir = blockIdx.y;
  const float* a = (dir ? an : ap) + h * NKI * RANKI;
  const float* b = (dir ? bn : bp) + h * RANKI * HD;
  for (int e = threadIdx.x; e < NKI * HD; e += 256) {
    int k = e >> 7, d = e & 127;
    float s = 0.0f;
#pragma unroll
    for (int r = 0; r < RANKI; ++r) s += a[k * RANKI + r] * b[r * HD + d];
    kk[e] = s;
  }
  __syncthreads();
  float* dt = (dir ? dtn : dtp) + (size_t)h * NTAP * HD;
  for (int e = threadIdx.x; e < NTAP * HD; e += 256) {
    int j = e >> 7, d = e & 127;
    int l = TAPS[j];
    float K0 = KinterpL(kk, l, d);
    float K1 = KinterpL(kk, l - 1, d);
    float K2 = KinterpL(kk, l - 2, d);
    dt[e] = K0 - 2.0f * GAMMA_F * K1 + (GAMMA_F * GAMMA_F) * K2;
  }
}

// ---------------- bf16 MFMA GEMM, double-buffered LDS, 32x32x16 ------------
// C = [silu](A @ Bt^T + bias). Tile = (MTILES*32) x 128, BK=32,
// global_load_lds width=16 (LDS unpadded, lane-ordered -- required by DMA).
// Wave tile = (MTILES*16) rows x 64 cols = MB x 2 blocks of 32x32.
// A/B frag: elem (lane&31, (lane>>5)*8 + j); C/D (verified, m74/m101):
//   col = lane&31, row = (reg&3) + 8*(reg>>2) + 4*(lane>>5).
// uv_mode: N=4096 fused u|v; n<2048 -> C (u), n>=2048 -> C2 (Vp, row-remapped).
template <int MTILES>
__global__ __launch_bounds__(256) void gemm_bf16(const unsigned short* __restrict__ A,
                                                 const unsigned short* __restrict__ Bt,
                                                 const float* __restrict__ bias,
                                                 const float* __restrict__ bias2,
                                                 void* __restrict__ C,
                                                 void* __restrict__ C2,
                                                 int M, int N, int K,
                                                 int do_silu, int c_fp32, int uv_mode) {
  constexpr int MB = MTILES / 2;                    // 32-row blocks per wave
  __shared__ unsigned short Al[2][MTILES * 1024];   // MTILES*32 rows x 32 elems
  __shared__ unsigned short Bl[2][4096];            // 128 rows x 32 elems
  int m0 = blockIdx.y * (MTILES * 32), n0 = blockIdx.x * 128;
  int tid = threadIdx.x;
  int lane = tid & 63, w = tid >> 6;
  int rw = (w >> 1) * (MTILES * 16), cw = (w & 1) * 64;
  int l32 = lane & 31, lh = lane >> 5;
  floatx16 acc[MB][2];
#pragma unroll
  for (int mb = 0; mb < MB; ++mb)
#pragma unroll
    for (int nb = 0; nb < 2; ++nb)
#pragma unroll
      for (int r = 0; r < 16; ++r) acc[mb][nb][r] = 0.f;
  int grow = tid >> 2;            // row 0..63 within a 64-row segment
  int gcol = (tid & 3) * 8;       // k-offset (elems), plain lane order
  const unsigned short* A0 = A + (size_t)(m0 + grow) * K + gcol;
  const unsigned short* A1 = A0 + (size_t)64 * K;
  const unsigned short* B0 = Bt + (size_t)(n0 + grow) * K + gcol;
  const unsigned short* B1 = B0 + (size_t)64 * K;
  int woff = w * 512;             // wave-uniform LDS element base
  int nIter = K >> 5;
  // prologue: stage iter 0 into buffer 0
  async16(A0, &Al[0][woff]);
  if (MTILES == 4) async16(A1, &Al[0][2048 + woff]);
  async16(B0, &Bl[0][woff]);
  async16(B1, &Bl[0][2048 + woff]);
  int p = 0;
  for (int i = 0; i < nIter; ++i) {
    __syncthreads();   // drains vmcnt: buffer p staged; prev reads of p^1 done
    if (i + 1 < nIter) {           // prefetch i+1 into p^1, overlaps MFMA below
      int kn = (i + 1) << 5;
      async16(A0 + kn, &Al[p ^ 1][woff]);
      if (MTILES == 4) async16(A1 + kn, &Al[p ^ 1][2048 + woff]);
      async16(B0 + kn, &Bl[p ^ 1][woff]);
      async16(B1 + kn, &Bl[p ^ 1][2048 + woff]);
    }
    short8 af[MB][2], bfr[2][2];
#pragma unroll
    for (int mb = 0; mb < MB; ++mb)
#pragma unroll
      for (int ks = 0; ks < 2; ++ks)
        af[mb][ks] = *(const short8*)(&Al[p][(rw + mb * 32 + l32) * 32 + ks * 16 + lh * 8]);
#pragma unroll
    for (int nb = 0; nb < 2; ++nb)
#pragma unroll
      for (int ks = 0; ks < 2; ++ks)
        bfr[nb][ks] = *(const short8*)(&Bl[p][(cw + nb * 32 + l32) * 32 + ks * 16 + lh * 8]);
#pragma unroll
    for (int mb = 0; mb < MB; ++mb)
#pragma unroll
      for (int nb = 0; nb < 2; ++nb)
#pragma unroll
        for (int ks = 0; ks < 2; ++ks)
          acc[mb][nb] = __builtin_amdgcn_mfma_f32_32x32x16_bf16(af[mb][ks], bfr[nb][ks], acc[mb][nb], 0, 0, 0);
    p ^= 1;
  }
  // epilogue
  int isv = uv_mode && (n0 >= 2048);
  int ldc = uv_mode ? 2048 : N;
  int ncb = isv ? (n0 - 2048) : n0;
  const float* buse = isv ? bias2 : bias;
#pragma unroll
  for (int mb = 0; mb < MB; ++mb) {
#pragma unroll
    for (int nb = 0; nb < 2; ++nb) {
      int n = ncb + cw + nb * 32 + l32;
      float bsv = buse[n];
      int mbase = m0 + rw + mb * 32 + 4 * lh;
#pragma unroll
      for (int r = 0; r < 16; ++r) {
        int m = mbase + (r & 3) + 8 * (r >> 2);
        float val = acc[mb][nb][r] + bsv;
        if (do_silu) val = val / (1.0f + __expf(-val));
        if (isv) {
          size_t mrow = (size_t)(2048 + m + ((m >> 11) << 12));  // padded-V row
          ((unsigned short*)C2)[mrow * 2048 + n] = f2bf(val);
        } else if (c_fp32) {
          ((float*)C)[(size_t)m * ldc + n] = val;
        } else {
          ((unsigned short*)C)[(size_t)m * ldc + n] = f2bf(val);
        }
      }
    }
  }
}

// ---------------- chunked IIR scan (phase A) -------------------------------
// delta in REGISTERS (launch_bounds(256,1)); pair-carry: 15 VMEM loads/step.
__global__ __launch_bounds__(256, 1) void scan_chunks(const unsigned short* __restrict__ Vp,
                                                      const float* __restrict__ dp,
                                                      const float* __restrict__ dn,
                                                      unsigned short* __restrict__ ypl,
                                                      unsigned short* __restrict__ ynl,
                                                      float* __restrict__ Sy_ex,
                                                      float* __restrict__ SG_ex) {
  int z = blockIdx.z;            // dir*2 + b
  int dir = z >> 1, b = z & 1;
  int chunk = blockIdx.y;
  int c0 = blockIdx.x * 512 + threadIdx.x * 2;   // two channels per thread
  int h = c0 >> 7, d = c0 & 127;
  const float* dt = (dir ? dn : dp) + ((size_t)h * NTAP) * HD + d;
  float2 dreg[NTAP];
#pragma unroll
  for (int j = 0; j < NTAP; ++j) dreg[j] = *(const float2*)(dt + j * HD);
  const unsigned short* Vb = Vp + (size_t)b * VPROWS * D1 + c0;
  unsigned short* yl = (dir ? ynl : ypl) + (size_t)b * NSEQ * D1 + c0;
  float sy0 = 0.f, sy1 = 0.f, sg0 = 0.f, sg1 = 0.f;
  float carry0[NPAIR], carry1[NPAIR];
  if (!dir) {
    int t0 = chunk * CLEN;
    const unsigned short* Vrow = Vb + (size_t)(2048 + t0) * D1;
#pragma unroll
    for (int p = 0; p < NPAIR; ++p) {
      unsigned int pk = *(const unsigned int*)(Vrow - (ptrdiff_t)(LEADL[p] + 1) * D1);
      carry0[p] = bflo(pk); carry1[p] = bfhi(pk);
    }
    for (int i = 0; i < CLEN; ++i) {
      float F0 = 0.f, F1 = 0.f;
#pragma unroll
      for (int p = 0; p < NPAIR; ++p) {
        unsigned int pk = *(const unsigned int*)(Vrow - (ptrdiff_t)LEADL[p] * D1);
        float vl0 = bflo(pk), vl1 = bfhi(pk);
        F0 += dreg[LEADI[p]].x * vl0 + dreg[LEADI[p] + 1].x * carry0[p];
        F1 += dreg[LEADI[p]].y * vl1 + dreg[LEADI[p] + 1].y * carry1[p];
        carry0[p] = vl0; carry1[p] = vl1;
      }
      {
        unsigned int pk = *(const unsigned int*)(Vrow - (ptrdiff_t)SGL0_L * D1);
        F0 += dreg[SGL0_I].x * bflo(pk); F1 += dreg[SGL0_I].y * bfhi(pk);
      }
      {
        unsigned int pk = *(const unsigned int*)(Vrow - (ptrdiff_t)SGL1_L * D1);
        F0 += dreg[SGL1_I].x * bflo(pk); F1 += dreg[SGL1_I].y * bfhi(pk);
      }
      sg0 = GAMMA_F * sg0 + F0; sy0 = GAMMA_F * sy0 + sg0;
      sg1 = GAMMA_F * sg1 + F1; sy1 = GAMMA_F * sy1 + sg1;
      unsigned int pack = (unsigned int)f2bf(sy0) | ((unsigned int)f2bf(sy1) << 16);
      *(unsigned int*)(yl + (size_t)(t0 + i) * D1) = pack;
      Vrow += D1;
    }
  } else {
    int tstart = (NSEQ - 1) - chunk * CLEN;        // reversed time
    const unsigned short* Vrow = Vb + (size_t)(2048 + tstart) * D1;
#pragma unroll
    for (int p = 0; p < NPAIR; ++p) {
      unsigned int pk = *(const unsigned int*)(Vrow + (ptrdiff_t)(LEADL[p] + 1) * D1);
      carry0[p] = bflo(pk); carry1[p] = bfhi(pk);
    }
    for (int i = 0; i < CLEN; ++i) {
      float F0 = 0.f, F1 = 0.f;
#pragma unroll
      for (int p = 0; p < NPAIR; ++p) {
        unsigned int pk = *(const unsigned int*)(Vrow + (ptrdiff_t)LEADL[p] * D1);
        float vl0 = bflo(pk), vl1 = bfhi(pk);
        F0 += dreg[LEADI[p]].x * vl0 + dreg[LEADI[p] + 1].x * carry0[p];
        F1 += dreg[LEADI[p]].y * vl1 + dreg[LEADI[p] + 1].y * carry1[p];
        carry0[p] = vl0; carry1[p] = vl1;
      }
      {
        unsigned int pk = *(const unsigned int*)(Vrow + (ptrdiff_t)SGL0_L * D1);
        F0 += dreg[SGL0_I].x * bflo(pk); F1 += dreg[SGL0_I].y * bfhi(pk);
      }
      {
        unsigned int pk = *(const unsigned int*)(Vrow + (ptrdiff_t)SGL1_L * D1);
        F0 += dreg[SGL1_I].x * bflo(pk); F1 += dreg[SGL1_I].y * bfhi(pk);
      }
      sg0 = GAMMA_F * sg0 + F0; sy0 = GAMMA_F * sy0 + sg0;
      sg1 = GAMMA_F * sg1 + F1; sy1 = GAMMA_F * sy1 + sg1;
      unsigned int pack = (unsigned int)f2bf(sy0) | ((unsigned int)f2bf(sy1) << 16);
      *(unsigned int*)(yl + (size_t)(tstart - i) * D1) = pack;
      Vrow -= D1;
    }
  }
  size_t sidx = ((size_t)z * NCHUNK + chunk) * D1 + c0;
  Sy_ex[sidx] = sy0; Sy_ex[sidx + 1] = sy1;
  SG_ex[sidx] = sg0; SG_ex[sidx + 1] = sg1;
}

// ---------------- chunk-state scan (phase B) -------------------------------
__global__ __launch_bounds__(256) void state_scan(const float* __restrict__ Sy_ex,
                                                  const float* __restrict__ SG_ex,
                                                  float* __restrict__ Sy_in,
                                                  float* __restrict__ SG_in) {
  int idx = blockIdx.x * 256 + threadIdx.x;   // z*2048 + c, total 4*2048
  if (idx >= 4 * D1) return;
  int z = idx >> 11, c = idx & (D1 - 1);
  float ey = 0.f, eg = 0.f;
  for (int k = 0; k < NCHUNK; ++k) {
    size_t s = ((size_t)z * NCHUNK + k) * D1 + c;
    Sy_in[s] = ey; SG_in[s] = eg;
    float lex = Sy_ex[s], lgx = SG_ex[s];
    ey = lex + G_CL * (ey + (float)CLEN * eg);
    eg = lgx + G_CL * eg;
  }
}

// ---------------- combine + gate (phase C), 4 channels/thread --------------
__global__ __launch_bounds__(256) void combine_kernel(const unsigned short* __restrict__ ypl,
                                                      const unsigned short* __restrict__ ynl,
                                                      const unsigned short* __restrict__ Vp,
                                                      const float* __restrict__ Sy_in,
                                                      const float* __restrict__ SG_in,
                                                      const float* __restrict__ tz,
                                                      const unsigned short* __restrict__ U,
                                                      unsigned short* __restrict__ G) {
  int e = blockIdx.x * 256 + threadIdx.x;     // quad index over [b][t][c/4]
  int cq = e & (D1 / 4 - 1);
  int c0 = cq * 4;
  int r = e >> 9;
  int t = r & (NSEQ - 1);
  int b = r >> 11;
  int kp = t >> 4;  float dpD = (float)((t & 15) + 1);
  int tau = (NSEQ - 1) - t;
  int kn = tau >> 4; float dnD = (float)((tau & 15) + 1);
  float gp = __expf(dpD * LN_G);
  float gn = __expf(dnD * LN_G);
  size_t ix = (size_t)r * D1 + c0;
  size_t sp = ((size_t)(b) * NCHUNK + kp) * D1 + c0;          // z = b (pos)
  size_t sn = ((size_t)(2 + b) * NCHUNK + kn) * D1 + c0;      // z = 2+b (neg)
  uint2 pyl = *(const uint2*)(ypl + ix);
  uint2 pyn = *(const uint2*)(ynl + ix);
  uint2 pv  = *(const uint2*)(Vp + ((size_t)b * VPROWS + 2048 + t) * D1 + c0);
  uint2 pu  = *(const uint2*)(U + ix);
  float4 syp = *(const float4*)(Sy_in + sp);
  float4 sgp = *(const float4*)(SG_in + sp);
  float4 syn = *(const float4*)(Sy_in + sn);
  float4 sgn = *(const float4*)(SG_in + sn);
  float4 tzv = *(const float4*)(tz + c0);
  float yv[4], uv[4], vv[4];
  yv[0] = bflo(pyl.x) + gp * (syp.x + dpD * sgp.x) + bflo(pyn.x) + gn * (syn.x + dnD * sgn.x);
  yv[1] = bfhi(pyl.x) + gp * (syp.y + dpD * sgp.y) + bfhi(pyn.x) + gn * (syn.y + dnD * sgn.y);
  yv[2] = bflo(pyl.y) + gp * (syp.z + dpD * sgp.z) + bflo(pyn.y) + gn * (syn.z + dnD * sgn.z);
  yv[3] = bfhi(pyl.y) + gp * (syp.w + dpD * sgp.w) + bfhi(pyn.y) + gn * (syn.w + dnD * sgn.w);
  vv[0] = bflo(pv.x); vv[1] = bfhi(pv.x); vv[2] = bflo(pv.y); vv[3] = bfhi(pv.y);
  uv[0] = bflo(pu.x); uv[1] = bfhi(pu.x); uv[2] = bflo(pu.y); uv[3] = bfhi(pu.y);
  float tza[4] = {tzv.x, tzv.y, tzv.z, tzv.w};
  uint2 og;
  unsigned short g0 = f2bf(uv[0] * (yv[0] + tza[0] * vv[0]));
  unsigned short g1 = f2bf(uv[1] * (yv[1] + tza[1] * vv[1]));
  unsigned short g2 = f2bf(uv[2] * (yv[2] + tza[2] * vv[2]));
  unsigned short g3 = f2bf(uv[3] * (yv[3] + tza[3] * vv[3]));
  og.x = (unsigned int)g0 | ((unsigned int)g1 << 16);
  og.y = (unsigned int)g2 | ((unsigned int)g3 << 16);
  *(uint2*)(G + ix) = og;
}

// ---------------------------------------------------------------------------
extern "C" void kernel_launch(void* const* d_in, const int* in_sizes, int n_in,
                              void* d_out, int out_size, void* d_ws, size_t ws_size,
                              hipStream_t stream) {
  const float* x      = (const float*)d_in[0];
  const float* Wu     = (const float*)d_in[1];
  const float* bu     = (const float*)d_in[2];
  const float* Wv     = (const float*)d_in[3];
  const float* bv     = (const float*)d_in[4];
  const float* Wo     = (const float*)d_in[5];
  const float* bo     = (const float*)d_in[6];
  const float* a_pos  = (const float*)d_in[7];
  const float* b_pos  = (const float*)d_in[8];
  const float* a_neg  = (const float*)d_in[9];
  const float* b_neg  = (const float*)d_in[10];
  const float* t_zero = (const float*)d_in[11];
  float* out = (float*)d_out;

  char* ws = (char*)d_ws;
  unsigned short* x_bf  = (unsigned short*)ws; ws += (size_t)MROWS * DM * 2;        //  8 MB
  unsigned short* u_ws  = (unsigned short*)ws; ws += (size_t)MROWS * D1 * 2;        // 16 MB (g in-place)
  unsigned short* Vp    = (unsigned short*)ws; ws += (size_t)BB * VPROWS * D1 * 2;  // 48 MB padded V
  unsigned short* ypl   = (unsigned short*)ws; ws += (size_t)MROWS * D1 * 2;        // 16 MB
  unsigned short* ynl   = (unsigned short*)ws; ws += (size_t)MROWS * D1 * 2;        // 16 MB
  unsigned short* WoT   = (unsigned short*)ws; ws += (size_t)DM * D1 * 2;           //  4 MB (dedicated)
  float* dtp   = (float*)ws; ws += (size_t)H * NTAP * HD * 4;                       // 229 KB (fp32!)
  float* dtn   = (float*)ws; ws += (size_t)H * NTAP * HD * 4;
  float* Sy_in = (float*)ws; ws += (size_t)4 * NCHUNK * D1 * 4;                     // 4 MB each
  float* SG_in = (float*)ws; ws += (size_t)4 * NCHUNK * D1 * 4;
  // exit-state arrays alias x_bf (dead after the uv-gemm, 8 MB = exactly fits)
  float* Sy_ex = (float*)x_bf;
  float* SG_ex = (float*)x_bf + (size_t)4 * NCHUNK * D1;
  // uv weight buffer aliases ypl (disjoint lifetime, stream-ordered)
  unsigned short* WT2 = ypl;

  dim3 tb256(256);
  dim3 tptb(32, 8);
  // prep: x->bf16 + zero V pads (one dispatch)
  prep_kernel<<<dim3((CVT4 + PAD16 + 255) / 256), tb256, 0, stream>>>(x, x_bf, Vp);
  // Wo transpose early (dedicated buffer, off the combine->outgemm path)
  tpc_kernel<<<dim3(DM / 32, D1 / 32, 1), tptb, 0, stream>>>(Wo, WoT, Wo, WoT, D1, DM);
  // low-rank kernel factors -> sparse fp32 delta tables (fused, both dirs)
  kdtab_kernel<<<dim3(H, 2), tb256, 0, stream>>>(a_pos, b_pos, a_neg, b_neg, dtp, dtn);
  // fused u|v gemm: Bt = [WuT ; WvT]  (N = 4096), 128x128 tiles
  tpc_kernel<<<dim3(D1 / 32, DM / 32, 2), tptb, 0, stream>>>(
      Wu, WT2, Wv, WT2 + (size_t)D1 * DM, DM, D1);
  gemm_bf16<4><<<dim3(2 * D1 / 128, MROWS / 128), tb256, 0, stream>>>(
      x_bf, WT2, bu, bv, u_ws, Vp, MROWS, 2 * D1, DM, 1, 0, 1);
  // IIR conv: chunked scans -> state scan -> combine+gate (in-place over u)
  scan_chunks<<<dim3(D1 / 512, NCHUNK, 4), tb256, 0, stream>>>(Vp, dtp, dtn, ypl, ynl, Sy_ex, SG_ex);
  state_scan<<<dim3((4 * D1 + 255) / 256), tb256, 0, stream>>>(Sy_ex, SG_ex, Sy_in, SG_in);
  combine_kernel<<<dim3((size_t)MROWS * D1 / 1024), tb256, 0, stream>>>(ypl, ynl, Vp, Sy_in, SG_in, t_zero, u_ws, u_ws);
  // out = g @ Wo + bo (fp32), 64x128 tiles -> 512 blocks = 2/CU
  gemm_bf16<2><<<dim3(DM / 128, MROWS / 64), tb256, 0, stream>>>(
      u_ws, WoT, bo, bo, out, out, MROWS, DM, D1, 0, 1, 0);
}

// Round 14
// 303.273 us; speedup vs baseline: 1.0614x; 1.0614x over previous
//
#include <hip/hip_runtime.h>
#include <hip/hip_bf16.h>
#include <stdint.h>
#include <stddef.h>

// Problem constants (fixed by the reference)
#define BB 2
#define NSEQ 2048
#define DM 1024
#define H 16
#define HD 128
#define D1 2048
#define NKI 16
#define RANKI 32
#define MROWS (BB * NSEQ)   // 4096 rows for all GEMMs
#define VPROWS 6144         // 2048 zero-pad | 2048 data | 2048 zero-pad
#define NTAP 28
#define NPAIR 13
#define NCHUNK 128
#define CLEN 16
#define GAMMA_F 0.999f
#define G_CL 0.9841201f     // 0.999^16 (chunk-length homogeneous decay)
// ln(0.999), for gamma^x = exp(x*ln_g)  (__exp2f collides with glibc; __expf is safe)
#define LN_G (-1.00050033e-3f)

// NOTE: delta must remain fp32 everywhere — h[tau] = (tau+1)g^tau amplifies
// delta errors by up to ~368 [R9]. Do NOT XOR-swizzle gemm LDS [R10/R11].
// Do NOT use 32x32x16 MFMA here: its fragment reads only cover 2 column
// positions per 64B LDS row -> 3x bank conflicts, uv 69->78 us [R13].
__device__ constexpr int TAPS[NTAP] = {
  1, 2, 138, 139, 274, 275, 411, 412, 547, 548, 684,
  820, 821, 956, 957, 1093, 1094, 1229, 1230, 1366,
  1502, 1503, 1638, 1639, 1775, 1776, 1911, 1912};
__device__ constexpr int LEADL[NPAIR] = {1, 138, 274, 411, 547, 820, 956, 1093, 1229, 1502, 1638, 1775, 1911};
__device__ constexpr int LEADI[NPAIR] = {0, 2, 4, 6, 8, 11, 13, 15, 17, 20, 22, 24, 26};
#define SGL0_L 684
#define SGL0_I 10
#define SGL1_L 1366
#define SGL1_I 19

typedef short short8 __attribute__((ext_vector_type(8)));
typedef float floatx4 __attribute__((ext_vector_type(4)));

__device__ __forceinline__ float bf2f(unsigned short u) {
  union { unsigned int i; float f; } v; v.i = ((unsigned int)u) << 16; return v.f;
}
__device__ __forceinline__ unsigned short f2bf(float f) {
  union { float f; unsigned int i; } v; v.f = f;
  unsigned int r = (v.i + 0x7FFFu + ((v.i >> 16) & 1u)) >> 16;
  return (unsigned short)r;
}
__device__ __forceinline__ float bflo(unsigned int p) {
  union { unsigned int i; float f; } v; v.i = p << 16; return v.f;
}
__device__ __forceinline__ float bfhi(unsigned int p) {
  union { unsigned int i; float f; } v; v.i = p & 0xffff0000u; return v.f;
}
// async 16B global->LDS DMA: lane i lands at (wave-uniform) l + i*16 bytes
__device__ __forceinline__ void async16(const unsigned short* g, unsigned short* l) {
  __builtin_amdgcn_global_load_lds(
      (const __attribute__((address_space(1))) unsigned int*)g,
      (__attribute__((address_space(3))) unsigned int*)l, 16, 0, 0);
}

// ------- prep: x fp32->bf16 convert + zero the 4 V pad regions (1 dispatch) -
#define CVT4 (MROWS * DM / 4)            // 1048576 float4->ushort4 units
#define PAD16 (4 * NSEQ * D1 / 8)        // 2097152 uint4 (8-short) pad writes
__global__ __launch_bounds__(256) void prep_kernel(const float* __restrict__ x,
                                                   unsigned short* __restrict__ x_bf,
                                                   unsigned short* __restrict__ Vp) {
  int i = blockIdx.x * 256 + threadIdx.x;
  if (i < CVT4) {
    float4 f = ((const float4*)x)[i];
    ushort4 o;
    o.x = f2bf(f.x); o.y = f2bf(f.y); o.z = f2bf(f.z); o.w = f2bf(f.w);
    ((ushort4*)x_bf)[i] = o;
  } else {
    int j = i - CVT4;
    if (j < PAD16) {
      int r = j >> 19;            // region 0..3, each 524288 uint4
      int off = j & 524287;
      const size_t bases[4] = {0, (size_t)4096 * D1, (size_t)VPROWS * D1,
                               (size_t)VPROWS * D1 + (size_t)4096 * D1};
      uint4 z; z.x = z.y = z.z = z.w = 0u;
      ((uint4*)(Vp + bases[r]))[off] = z;
    }
  }
}

// ------- fused transpose+convert: out_bf16[c][r] = in_f32[r][c] ------------
__global__ __launch_bounds__(256) void tpc_kernel(const float* __restrict__ inA,
                                                  unsigned short* __restrict__ outA,
                                                  const float* __restrict__ inB,
                                                  unsigned short* __restrict__ outB,
                                                  int rows, int cols) {
  __shared__ unsigned short t[32][33];
  const float* in = blockIdx.z ? inB : inA;
  unsigned short* out = blockIdx.z ? outB : outA;
  int bx = blockIdx.x * 32, by = blockIdx.y * 32;
  int tx = threadIdx.x, ty = threadIdx.y; // blockDim = (32,8)
#pragma unroll
  for (int j = 0; j < 32; j += 8)
    t[ty + j][tx] = f2bf(in[(size_t)(by + ty + j) * cols + bx + tx]);
  __syncthreads();
#pragma unroll
  for (int j = 0; j < 32; j += 8)
    out[(size_t)(bx + ty + j) * rows + by + tx] = t[tx][ty + j];
}

// ---- K(l) = interp(kind, l) * gamma^l on an LDS copy of kind --------------
__device__ __forceinline__ float KinterpL(const float* kk, int l, int d) {
  if (l < 1) return 0.0f;   // l > 2047 never queried (max tap 1912)
  float p = (float)(l - 1) * (15.0f / 2046.0f);
  int lo = (int)p; if (lo > 15) lo = 15;
  int hi = lo + 1; if (hi > 15) hi = 15;
  float w = p - (float)lo;
  float v = kk[lo * HD + d] * (1.0f - w) + kk[hi * HD + d] * w;
  return v * __powf(GAMMA_F, (float)l);
}

// ---- fused: kind = a@b per (head,dir) -> fp32 delta table at taps ---------
__global__ __launch_bounds__(256) void kdtab_kernel(const float* __restrict__ ap,
                                                    const float* __restrict__ bp,
                                                    const float* __restrict__ an,
                                                    const float* __restrict__ bn,
                                                    float* __restrict__ dtp,
                                                    float* __restrict__ dtn) {
  __shared__ float kk[NKI * HD];  // 8 KB
  int h = blockIdx.x, dir = blockIdx.y;
  const float* a = (dir ? an : ap) + h * NKI * RANKI;
  const float* b = (dir ? bn : bp) + h * RANKI * HD;
  for (int e = threadIdx.x; e < NKI * HD; e += 256) {
    int k = e >> 7, d = e & 127;
    float s = 0.0f;
#pragma unroll
    for (int r = 0; r < RANKI; ++r) s += a[k * RANKI + r] * b[r * HD + d];
    kk[e] = s;
  }
  __syncthreads();
  float* dt = (dir ? dtn : dtp) + (size_t)h * NTAP * HD;
  for (int e = threadIdx.x; e < NTAP * HD; e += 256) {
    int j = e >> 7, d = e & 127;
    int l = TAPS[j];
    float K0 = KinterpL(kk, l, d);
    float K1 = KinterpL(kk, l - 1, d);
    float K2 = KinterpL(kk, l - 2, d);
    dt[e] = K0 - 2.0f * GAMMA_F * K1 + (GAMMA_F * GAMMA_F) * K2;
  }
}

// ---------------- bf16 MFMA GEMM, double-buffered LDS, 16x16x32 ------------
// C = [silu](A @ Bt^T + bias). Tile = (MTILES*32) x 128, k-step = KCH*32,
// global_load_lds width=16 (LDS unpadded, lane-ordered -- required by DMA).
// Each of the KCH k-chunks is an independent 32-elem-row region (the verified
// conflict-free R12 layout); KCH=2 halves barrier count for long-K gemms.
// uv_mode: N=4096 fused u|v; n<2048 -> C (u), n>=2048 -> C2 (Vp, row-remapped).
template <int MTILES, int KCH>
__global__ __launch_bounds__(256) void gemm_bf16(const unsigned short* __restrict__ A,
                                                 const unsigned short* __restrict__ Bt,
                                                 const float* __restrict__ bias,
                                                 const float* __restrict__ bias2,
                                                 void* __restrict__ C,
                                                 void* __restrict__ C2,
                                                 int M, int N, int K,
                                                 int do_silu, int c_fp32, int uv_mode) {
  constexpr int AREG = MTILES * 1024;               // elems per A k-chunk region
  constexpr int BREG = 4096;                        // elems per B k-chunk region
  __shared__ unsigned short Al[2][AREG * KCH];
  __shared__ unsigned short Bl[2][BREG * KCH];
  int m0 = blockIdx.y * (MTILES * 32), n0 = blockIdx.x * 128;
  int tid = threadIdx.x;
  int lane = tid & 63, w = tid >> 6;
  int rw = (w >> 1) * (MTILES * 16), cw = (w & 1) * 64;
  int q = lane >> 4, l16 = lane & 15;
  floatx4 acc[MTILES][4];
#pragma unroll
  for (int mt = 0; mt < MTILES; ++mt)
#pragma unroll
    for (int nt = 0; nt < 4; ++nt) acc[mt][nt] = (floatx4){0.f, 0.f, 0.f, 0.f};
  int grow = tid >> 2;            // row 0..63 within a 64-row segment
  int gcol = (tid & 3) * 8;       // k-offset (elems), plain lane order
  const unsigned short* A0 = A + (size_t)(m0 + grow) * K + gcol;
  const unsigned short* A1 = A0 + (size_t)64 * K;
  const unsigned short* B0 = Bt + (size_t)(n0 + grow) * K + gcol;
  const unsigned short* B1 = B0 + (size_t)64 * K;
  int woff = w * 512;             // wave-uniform LDS element base
  int nIter = K / (32 * KCH);
  // prologue: stage iter 0 into buffer 0
#pragma unroll
  for (int kc = 0; kc < KCH; ++kc) {
    async16(A0 + kc * 32, &Al[0][kc * AREG + woff]);
    if (MTILES == 4) async16(A1 + kc * 32, &Al[0][kc * AREG + 2048 + woff]);
    async16(B0 + kc * 32, &Bl[0][kc * BREG + woff]);
    async16(B1 + kc * 32, &Bl[0][kc * BREG + 2048 + woff]);
  }
  int p = 0;
  for (int i = 0; i < nIter; ++i) {
    __syncthreads();   // drains vmcnt: buffer p staged; prev reads of p^1 done
    if (i + 1 < nIter) {           // prefetch i+1 into p^1, overlaps MFMA below
      int kn = (i + 1) * 32 * KCH;
#pragma unroll
      for (int kc = 0; kc < KCH; ++kc) {
        async16(A0 + kn + kc * 32, &Al[p ^ 1][kc * AREG + woff]);
        if (MTILES == 4) async16(A1 + kn + kc * 32, &Al[p ^ 1][kc * AREG + 2048 + woff]);
        async16(B0 + kn + kc * 32, &Bl[p ^ 1][kc * BREG + woff]);
        async16(B1 + kn + kc * 32, &Bl[p ^ 1][kc * BREG + 2048 + woff]);
      }
    }
#pragma unroll
    for (int kc = 0; kc < KCH; ++kc) {
      short8 af[MTILES], bfr[4];
#pragma unroll
      for (int i4 = 0; i4 < MTILES; ++i4)
        af[i4] = *(const short8*)(&Al[p][kc * AREG + (rw + i4 * 16 + l16) * 32 + q * 8]);
#pragma unroll
      for (int i4 = 0; i4 < 4; ++i4)
        bfr[i4] = *(const short8*)(&Bl[p][kc * BREG + (cw + i4 * 16 + l16) * 32 + q * 8]);
#pragma unroll
      for (int mt = 0; mt < MTILES; ++mt)
#pragma unroll
        for (int nt = 0; nt < 4; ++nt)
          acc[mt][nt] = __builtin_amdgcn_mfma_f32_16x16x32_bf16(af[mt], bfr[nt], acc[mt][nt], 0, 0, 0);
    }
    p ^= 1;
  }
  // epilogue: D[row = q*4 + r][col = lane&15] per 16x16 tile (verified mapping)
  int isv = uv_mode && (n0 >= 2048);
  int ldc = uv_mode ? 2048 : N;
  int ncb = isv ? (n0 - 2048) : n0;
  const float* buse = isv ? bias2 : bias;
#pragma unroll
  for (int mt = 0; mt < MTILES; ++mt) {
#pragma unroll
    for (int nt = 0; nt < 4; ++nt) {
      int n = ncb + cw + nt * 16 + l16;
      float bsv = buse[n];
#pragma unroll
      for (int r = 0; r < 4; ++r) {
        int m = m0 + rw + mt * 16 + q * 4 + r;
        float val = acc[mt][nt][r] + bsv;
        if (do_silu) val = val / (1.0f + __expf(-val));
        if (isv) {
          size_t mrow = (size_t)(2048 + m + ((m >> 11) << 12));  // padded-V row
          ((unsigned short*)C2)[mrow * 2048 + n] = f2bf(val);
        } else if (c_fp32) {
          ((float*)C)[(size_t)m * ldc + n] = val;
        } else {
          ((unsigned short*)C)[(size_t)m * ldc + n] = f2bf(val);
        }
      }
    }
  }
}

// ---------------- chunked IIR scan (phase A) -------------------------------
// delta in REGISTERS (launch_bounds(256,1)); pair-carry: 15 VMEM loads/step.
__global__ __launch_bounds__(256, 1) void scan_chunks(const unsigned short* __restrict__ Vp,
                                                      const float* __restrict__ dp,
                                                      const float* __restrict__ dn,
                                                      unsigned short* __restrict__ ypl,
                                                      unsigned short* __restrict__ ynl,
                                                      float* __restrict__ Sy_ex,
                                                      float* __restrict__ SG_ex) {
  int z = blockIdx.z;            // dir*2 + b
  int dir = z >> 1, b = z & 1;
  int chunk = blockIdx.y;
  int c0 = blockIdx.x * 512 + threadIdx.x * 2;   // two channels per thread
  int h = c0 >> 7, d = c0 & 127;
  const float* dt = (dir ? dn : dp) + ((size_t)h * NTAP) * HD + d;
  float2 dreg[NTAP];
#pragma unroll
  for (int j = 0; j < NTAP; ++j) dreg[j] = *(const float2*)(dt + j * HD);
  const unsigned short* Vb = Vp + (size_t)b * VPROWS * D1 + c0;
  unsigned short* yl = (dir ? ynl : ypl) + (size_t)b * NSEQ * D1 + c0;
  float sy0 = 0.f, sy1 = 0.f, sg0 = 0.f, sg1 = 0.f;
  float carry0[NPAIR], carry1[NPAIR];
  if (!dir) {
    int t0 = chunk * CLEN;
    const unsigned short* Vrow = Vb + (size_t)(2048 + t0) * D1;
#pragma unroll
    for (int p = 0; p < NPAIR; ++p) {
      unsigned int pk = *(const unsigned int*)(Vrow - (ptrdiff_t)(LEADL[p] + 1) * D1);
      carry0[p] = bflo(pk); carry1[p] = bfhi(pk);
    }
    for (int i = 0; i < CLEN; ++i) {
      float F0 = 0.f, F1 = 0.f;
#pragma unroll
      for (int p = 0; p < NPAIR; ++p) {
        unsigned int pk = *(const unsigned int*)(Vrow - (ptrdiff_t)LEADL[p] * D1);
        float vl0 = bflo(pk), vl1 = bfhi(pk);
        F0 += dreg[LEADI[p]].x * vl0 + dreg[LEADI[p] + 1].x * carry0[p];
        F1 += dreg[LEADI[p]].y * vl1 + dreg[LEADI[p] + 1].y * carry1[p];
        carry0[p] = vl0; carry1[p] = vl1;
      }
      {
        unsigned int pk = *(const unsigned int*)(Vrow - (ptrdiff_t)SGL0_L * D1);
        F0 += dreg[SGL0_I].x * bflo(pk); F1 += dreg[SGL0_I].y * bfhi(pk);
      }
      {
        unsigned int pk = *(const unsigned int*)(Vrow - (ptrdiff_t)SGL1_L * D1);
        F0 += dreg[SGL1_I].x * bflo(pk); F1 += dreg[SGL1_I].y * bfhi(pk);
      }
      sg0 = GAMMA_F * sg0 + F0; sy0 = GAMMA_F * sy0 + sg0;
      sg1 = GAMMA_F * sg1 + F1; sy1 = GAMMA_F * sy1 + sg1;
      unsigned int pack = (unsigned int)f2bf(sy0) | ((unsigned int)f2bf(sy1) << 16);
      *(unsigned int*)(yl + (size_t)(t0 + i) * D1) = pack;
      Vrow += D1;
    }
  } else {
    int tstart = (NSEQ - 1) - chunk * CLEN;        // reversed time
    const unsigned short* Vrow = Vb + (size_t)(2048 + tstart) * D1;
#pragma unroll
    for (int p = 0; p < NPAIR; ++p) {
      unsigned int pk = *(const unsigned int*)(Vrow + (ptrdiff_t)(LEADL[p] + 1) * D1);
      carry0[p] = bflo(pk); carry1[p] = bfhi(pk);
    }
    for (int i = 0; i < CLEN; ++i) {
      float F0 = 0.f, F1 = 0.f;
#pragma unroll
      for (int p = 0; p < NPAIR; ++p) {
        unsigned int pk = *(const unsigned int*)(Vrow + (ptrdiff_t)LEADL[p] * D1);
        float vl0 = bflo(pk), vl1 = bfhi(pk);
        F0 += dreg[LEADI[p]].x * vl0 + dreg[LEADI[p] + 1].x * carry0[p];
        F1 += dreg[LEADI[p]].y * vl1 + dreg[LEADI[p] + 1].y * carry1[p];
        carry0[p] = vl0; carry1[p] = vl1;
      }
      {
        unsigned int pk = *(const unsigned int*)(Vrow + (ptrdiff_t)SGL0_L * D1);
        F0 += dreg[SGL0_I].x * bflo(pk); F1 += dreg[SGL0_I].y * bfhi(pk);
      }
      {
        unsigned int pk = *(const unsigned int*)(Vrow + (ptrdiff_t)SGL1_L * D1);
        F0 += dreg[SGL1_I].x * bflo(pk); F1 += dreg[SGL1_I].y * bfhi(pk);
      }
      sg0 = GAMMA_F * sg0 + F0; sy0 = GAMMA_F * sy0 + sg0;
      sg1 = GAMMA_F * sg1 + F1; sy1 = GAMMA_F * sy1 + sg1;
      unsigned int pack = (unsigned int)f2bf(sy0) | ((unsigned int)f2bf(sy1) << 16);
      *(unsigned int*)(yl + (size_t)(tstart - i) * D1) = pack;
      Vrow -= D1;
    }
  }
  size_t sidx = ((size_t)z * NCHUNK + chunk) * D1 + c0;
  Sy_ex[sidx] = sy0; Sy_ex[sidx + 1] = sy1;
  SG_ex[sidx] = sg0; SG_ex[sidx + 1] = sg1;
}

// ---------------- chunk-state scan (phase B) -------------------------------
__global__ __launch_bounds__(256) void state_scan(const float* __restrict__ Sy_ex,
                                                  const float* __restrict__ SG_ex,
                                                  float* __restrict__ Sy_in,
                                                  float* __restrict__ SG_in) {
  int idx = blockIdx.x * 256 + threadIdx.x;   // z*2048 + c, total 4*2048
  if (idx >= 4 * D1) return;
  int z = idx >> 11, c = idx & (D1 - 1);
  float ey = 0.f, eg = 0.f;
  for (int k = 0; k < NCHUNK; ++k) {
    size_t s = ((size_t)z * NCHUNK + k) * D1 + c;
    Sy_in[s] = ey; SG_in[s] = eg;
    float lex = Sy_ex[s], lgx = SG_ex[s];
    ey = lex + G_CL * (ey + (float)CLEN * eg);
    eg = lgx + G_CL * eg;
  }
}

// ---------------- combine + gate (phase C), 4 channels/thread --------------
__global__ __launch_bounds__(256) void combine_kernel(const unsigned short* __restrict__ ypl,
                                                      const unsigned short* __restrict__ ynl,
                                                      const unsigned short* __restrict__ Vp,
                                                      const float* __restrict__ Sy_in,
                                                      const float* __restrict__ SG_in,
                                                      const float* __restrict__ tz,
                                                      const unsigned short* __restrict__ U,
                                                      unsigned short* __restrict__ G) {
  int e = blockIdx.x * 256 + threadIdx.x;     // quad index over [b][t][c/4]
  int cq = e & (D1 / 4 - 1);
  int c0 = cq * 4;
  int r = e >> 9;
  int t = r & (NSEQ - 1);
  int b = r >> 11;
  int kp = t >> 4;  float dpD = (float)((t & 15) + 1);
  int tau = (NSEQ - 1) - t;
  int kn = tau >> 4; float dnD = (float)((tau & 15) + 1);
  float gp = __expf(dpD * LN_G);
  float gn = __expf(dnD * LN_G);
  size_t ix = (size_t)r * D1 + c0;
  size_t sp = ((size_t)(b) * NCHUNK + kp) * D1 + c0;          // z = b (pos)
  size_t sn = ((size_t)(2 + b) * NCHUNK + kn) * D1 + c0;      // z = 2+b (neg)
  uint2 pyl = *(const uint2*)(ypl + ix);
  uint2 pyn = *(const uint2*)(ynl + ix);
  uint2 pv  = *(const uint2*)(Vp + ((size_t)b * VPROWS + 2048 + t) * D1 + c0);
  uint2 pu  = *(const uint2*)(U + ix);
  float4 syp = *(const float4*)(Sy_in + sp);
  float4 sgp = *(const float4*)(SG_in + sp);
  float4 syn = *(const float4*)(Sy_in + sn);
  float4 sgn = *(const float4*)(SG_in + sn);
  float4 tzv = *(const float4*)(tz + c0);
  float yv[4], uv[4], vv[4];
  yv[0] = bflo(pyl.x) + gp * (syp.x + dpD * sgp.x) + bflo(pyn.x) + gn * (syn.x + dnD * sgn.x);
  yv[1] = bfhi(pyl.x) + gp * (syp.y + dpD * sgp.y) + bfhi(pyn.x) + gn * (syn.y + dnD * sgn.y);
  yv[2] = bflo(pyl.y) + gp * (syp.z + dpD * sgp.z) + bflo(pyn.y) + gn * (syn.z + dnD * sgn.z);
  yv[3] = bfhi(pyl.y) + gp * (syp.w + dpD * sgp.w) + bfhi(pyn.y) + gn * (syn.w + dnD * sgn.w);
  vv[0] = bflo(pv.x); vv[1] = bfhi(pv.x); vv[2] = bflo(pv.y); vv[3] = bfhi(pv.y);
  uv[0] = bflo(pu.x); uv[1] = bfhi(pu.x); uv[2] = bflo(pu.y); uv[3] = bfhi(pu.y);
  float tza[4] = {tzv.x, tzv.y, tzv.z, tzv.w};
  uint2 og;
  unsigned short g0 = f2bf(uv[0] * (yv[0] + tza[0] * vv[0]));
  unsigned short g1 = f2bf(uv[1] * (yv[1] + tza[1] * vv[1]));
  unsigned short g2 = f2bf(uv[2] * (yv[2] + tza[2] * vv[2]));
  unsigned short g3 = f2bf(uv[3] * (yv[3] + tza[3] * vv[3]));
  og.x = (unsigned int)g0 | ((unsigned int)g1 << 16);
  og.y = (unsigned int)g2 | ((unsigned int)g3 << 16);
  *(uint2*)(G + ix) = og;
}

// ---------------------------------------------------------------------------
extern "C" void kernel_launch(void* const* d_in, const int* in_sizes, int n_in,
                              void* d_out, int out_size, void* d_ws, size_t ws_size,
                              hipStream_t stream) {
  const float* x      = (const float*)d_in[0];
  const float* Wu     = (const float*)d_in[1];
  const float* bu     = (const float*)d_in[2];
  const float* Wv     = (const float*)d_in[3];
  const float* bv     = (const float*)d_in[4];
  const float* Wo     = (const float*)d_in[5];
  const float* bo     = (const float*)d_in[6];
  const float* a_pos  = (const float*)d_in[7];
  const float* b_pos  = (const float*)d_in[8];
  const float* a_neg  = (const float*)d_in[9];
  const float* b_neg  = (const float*)d_in[10];
  const float* t_zero = (const float*)d_in[11];
  float* out = (float*)d_out;

  char* ws = (char*)d_ws;
  unsigned short* x_bf  = (unsigned short*)ws; ws += (size_t)MROWS * DM * 2;        //  8 MB
  unsigned short* u_ws  = (unsigned short*)ws; ws += (size_t)MROWS * D1 * 2;        // 16 MB (g in-place)
  unsigned short* Vp    = (unsigned short*)ws; ws += (size_t)BB * VPROWS * D1 * 2;  // 48 MB padded V
  unsigned short* ypl   = (unsigned short*)ws; ws += (size_t)MROWS * D1 * 2;        // 16 MB
  unsigned short* ynl   = (unsigned short*)ws; ws += (size_t)MROWS * D1 * 2;        // 16 MB
  unsigned short* WoT   = (unsigned short*)ws; ws += (size_t)DM * D1 * 2;           //  4 MB (dedicated)
  float* dtp   = (float*)ws; ws += (size_t)H * NTAP * HD * 4;                       // 229 KB (fp32!)
  float* dtn   = (float*)ws; ws += (size_t)H * NTAP * HD * 4;
  float* Sy_in = (float*)ws; ws += (size_t)4 * NCHUNK * D1 * 4;                     // 4 MB each
  float* SG_in = (float*)ws; ws += (size_t)4 * NCHUNK * D1 * 4;
  // exit-state arrays alias x_bf (dead after the uv-gemm, 8 MB = exactly fits)
  float* Sy_ex = (float*)x_bf;
  float* SG_ex = (float*)x_bf + (size_t)4 * NCHUNK * D1;
  // uv weight buffer aliases ypl (disjoint lifetime, stream-ordered)
  unsigned short* WT2 = ypl;

  dim3 tb256(256);
  dim3 tptb(32, 8);
  // prep: x->bf16 + zero V pads (one dispatch)
  prep_kernel<<<dim3((CVT4 + PAD16 + 255) / 256), tb256, 0, stream>>>(x, x_bf, Vp);
  // Wo transpose early (dedicated buffer, off the combine->outgemm path)
  tpc_kernel<<<dim3(DM / 32, D1 / 32, 1), tptb, 0, stream>>>(Wo, WoT, Wo, WoT, D1, DM);
  // low-rank kernel factors -> sparse fp32 delta tables (fused, both dirs)
  kdtab_kernel<<<dim3(H, 2), tb256, 0, stream>>>(a_pos, b_pos, a_neg, b_neg, dtp, dtn);
  // fused u|v gemm: Bt = [WuT ; WvT]  (N = 4096), 128x128 tiles, KCH=1
  tpc_kernel<<<dim3(D1 / 32, DM / 32, 2), tptb, 0, stream>>>(
      Wu, WT2, Wv, WT2 + (size_t)D1 * DM, DM, D1);
  gemm_bf16<4, 1><<<dim3(2 * D1 / 128, MROWS / 128), tb256, 0, stream>>>(
      x_bf, WT2, bu, bv, u_ws, Vp, MROWS, 2 * D1, DM, 1, 0, 1);
  // IIR conv: chunked scans -> state scan -> combine+gate (in-place over u)
  scan_chunks<<<dim3(D1 / 512, NCHUNK, 4), tb256, 0, stream>>>(Vp, dtp, dtn, ypl, ynl, Sy_ex, SG_ex);
  state_scan<<<dim3((4 * D1 + 255) / 256), tb256, 0, stream>>>(Sy_ex, SG_ex, Sy_in, SG_in);
  combine_kernel<<<dim3((size_t)MROWS * D1 / 1024), tb256, 0, stream>>>(ypl, ynl, Vp, Sy_in, SG_in, t_zero, u_ws, u_ws);
  // out = g @ Wo + bo (fp32), 64x128 tiles, KCH=2 (BK=64, half the barriers)
  gemm_bf16<2, 2><<<dim3(DM / 128, MROWS / 64), tb256, 0, stream>>>(
      u_ws, WoT, bo, bo, out, out, MROWS, DM, D1, 0, 1, 0);
}

// Round 15
// 296.545 us; speedup vs baseline: 1.0855x; 1.0227x over previous
//
#include <hip/hip_runtime.h>
#include <hip/hip_bf16.h>
#include <stdint.h>
#include <stddef.h>

// Problem constants (fixed by the reference)
#define BB 2
#define NSEQ 2048
#define DM 1024
#define H 16
#define HD 128
#define D1 2048
#define NKI 16
#define RANKI 32
#define MROWS (BB * NSEQ)   // 4096 rows for all GEMMs
#define VPROWS 6144         // 2048 zero-pad | 2048 data | 2048 zero-pad
#define NTAP 28
#define NPAIR 13
#define NCHUNK 128
#define CLEN 16
#define GAMMA_F 0.999f
#define G_CL 0.9841201f     // 0.999^16 (chunk-length homogeneous decay)
#define LN_G (-1.00050033e-3f)

// NOTE: delta must remain fp32 everywhere [R9]. No XOR swizzle [R10/R11].
// No 32x32x16 MFMA (bank conflicts) [R13]. uv-gemm must stay the exact R12
// body — wrapping it in a KCH template perturbed codegen (VGPR 80->84,
// profiled 69->99 us) even at KCH=1 [R14].
__device__ constexpr int TAPS[NTAP] = {
  1, 2, 138, 139, 274, 275, 411, 412, 547, 548, 684,
  820, 821, 956, 957, 1093, 1094, 1229, 1230, 1366,
  1502, 1503, 1638, 1639, 1775, 1776, 1911, 1912};
__device__ constexpr int LEADL[NPAIR] = {1, 138, 274, 411, 547, 820, 956, 1093, 1229, 1502, 1638, 1775, 1911};
__device__ constexpr int LEADI[NPAIR] = {0, 2, 4, 6, 8, 11, 13, 15, 17, 20, 22, 24, 26};
#define SGL0_L 684
#define SGL0_I 10
#define SGL1_L 1366
#define SGL1_I 19

typedef short short8 __attribute__((ext_vector_type(8)));
typedef float floatx4 __attribute__((ext_vector_type(4)));

__device__ __forceinline__ float bf2f(unsigned short u) {
  union { unsigned int i; float f; } v; v.i = ((unsigned int)u) << 16; return v.f;
}
__device__ __forceinline__ unsigned short f2bf(float f) {
  union { float f; unsigned int i; } v; v.f = f;
  unsigned int r = (v.i + 0x7FFFu + ((v.i >> 16) & 1u)) >> 16;
  return (unsigned short)r;
}
__device__ __forceinline__ float bflo(unsigned int p) {
  union { unsigned int i; float f; } v; v.i = p << 16; return v.f;
}
__device__ __forceinline__ float bfhi(unsigned int p) {
  union { unsigned int i; float f; } v; v.i = p & 0xffff0000u; return v.f;
}
// async 16B global->LDS DMA: lane i lands at (wave-uniform) l + i*16 bytes
__device__ __forceinline__ void async16(const unsigned short* g, unsigned short* l) {
  __builtin_amdgcn_global_load_lds(
      (const __attribute__((address_space(1))) unsigned int*)g,
      (__attribute__((address_space(3))) unsigned int*)l, 16, 0, 0);
}

// ------- prep: x fp32->bf16 convert + zero the 4 V pad regions (1 dispatch) -
#define CVT4 (MROWS * DM / 4)            // 1048576 float4->ushort4 units
#define PAD16 (4 * NSEQ * D1 / 8)        // 2097152 uint4 (8-short) pad writes
__global__ __launch_bounds__(256) void prep_kernel(const float* __restrict__ x,
                                                   unsigned short* __restrict__ x_bf,
                                                   unsigned short* __restrict__ Vp) {
  int i = blockIdx.x * 256 + threadIdx.x;
  if (i < CVT4) {
    float4 f = ((const float4*)x)[i];
    ushort4 o;
    o.x = f2bf(f.x); o.y = f2bf(f.y); o.z = f2bf(f.z); o.w = f2bf(f.w);
    ((ushort4*)x_bf)[i] = o;
  } else {
    int j = i - CVT4;
    if (j < PAD16) {
      int r = j >> 19;            // region 0..3, each 524288 uint4
      int off = j & 524287;
      const size_t bases[4] = {0, (size_t)4096 * D1, (size_t)VPROWS * D1,
                               (size_t)VPROWS * D1 + (size_t)4096 * D1};
      uint4 z; z.x = z.y = z.z = z.w = 0u;
      ((uint4*)(Vp + bases[r]))[off] = z;
    }
  }
}

// ---- K(l) = interp(kind, l) * gamma^l on an LDS copy of kind --------------
__device__ __forceinline__ float KinterpL(const float* kk, int l, int d) {
  if (l < 1) return 0.0f;   // l > 2047 never queried (max tap 1912)
  float p = (float)(l - 1) * (15.0f / 2046.0f);
  int lo = (int)p; if (lo > 15) lo = 15;
  int hi = lo + 1; if (hi > 15) hi = 15;
  float w = p - (float)lo;
  float v = kk[lo * HD + d] * (1.0f - w) + kk[hi * HD + d] * w;
  return v * __powf(GAMMA_F, (float)l);
}

// ---- fused weight prep: Wo transpose | Wu/Wv transposes | kdtab -----------
// blockIdx.x ranges: [0,2048) Wo tiles; [2048,6144) uv tiles; [6144,6176) kdtab.
__global__ __launch_bounds__(256) void wprep_kernel(const float* __restrict__ Wu,
                                                    const float* __restrict__ Wv,
                                                    const float* __restrict__ Wo,
                                                    unsigned short* __restrict__ WT2,
                                                    unsigned short* __restrict__ WoT,
                                                    const float* __restrict__ ap,
                                                    const float* __restrict__ bp,
                                                    const float* __restrict__ an,
                                                    const float* __restrict__ bn,
                                                    float* __restrict__ dtp,
                                                    float* __restrict__ dtn) {
  int blk = blockIdx.x;
  int tid = threadIdx.x;
  if (blk < 6144) {
    __shared__ unsigned short t[32][33];
    const float* in; unsigned short* out;
    int rows, cols, bx, by;
    if (blk < 2048) {           // Wo [D1][DM] -> WoT [DM][D1]; grid was (32,64)
      in = Wo; out = WoT; rows = D1; cols = DM;
      bx = (blk & 31) * 32; by = (blk >> 5) * 32;
    } else {                    // Wu/Wv [DM][D1] -> WT2 [2*D1][DM]; grid (64,32,2)
      int local = blk - 2048;
      int z = local >> 11, l2 = local & 2047;
      in = z ? Wv : Wu; out = WT2 + (size_t)z * D1 * DM;
      rows = DM; cols = D1;
      bx = (l2 & 63) * 32; by = (l2 >> 6) * 32;
    }
    int tx = tid & 31, ty = tid >> 5;   // (32,8) flattened
#pragma unroll
    for (int j = 0; j < 32; j += 8)
      t[ty + j][tx] = f2bf(in[(size_t)(by + ty + j) * cols + bx + tx]);
    __syncthreads();
#pragma unroll
    for (int j = 0; j < 32; j += 8)
      out[(size_t)(bx + ty + j) * rows + by + tx] = t[tx][ty + j];
  } else {                      // kdtab: 32 blocks = (h, dir)
    __shared__ float kk[NKI * HD];  // 8 KB
    int e0 = blk - 6144;
    int h = e0 & 15, dir = e0 >> 4;
    const float* a = (dir ? an : ap) + h * NKI * RANKI;
    const float* b = (dir ? bn : bp) + h * RANKI * HD;
    for (int e = tid; e < NKI * HD; e += 256) {
      int k = e >> 7, d = e & 127;
      float s = 0.0f;
#pragma unroll
      for (int r = 0; r < RANKI; ++r) s += a[k * RANKI + r] * b[r * HD + d];
      kk[e] = s;
    }
    __syncthreads();
    float* dt = (dir ? dtn : dtp) + (size_t)h * NTAP * HD;
    for (int e = tid; e < NTAP * HD; e += 256) {
      int j = e >> 7, d = e & 127;
      int l = TAPS[j];
      float K0 = KinterpL(kk, l, d);
      float K1 = KinterpL(kk, l - 1, d);
      float K2 = KinterpL(kk, l - 2, d);
      dt[e] = K0 - 2.0f * GAMMA_F * K1 + (GAMMA_F * GAMMA_F) * K2;
    }
  }
}

// ---------------- uv GEMM: exact R12 body (do not touch — see note) --------
// C = silu(A @ Bt^T + bias). 128x128 tile, BK=32, dbuf LDS,
// global_load_lds width=16. N=4096 fused u|v; n>=2048 -> Vp (row-remapped).
template <int MTILES>
__global__ __launch_bounds__(256) void gemm_uv(const unsigned short* __restrict__ A,
                                               const unsigned short* __restrict__ Bt,
                                               const float* __restrict__ bias,
                                               const float* __restrict__ bias2,
                                               void* __restrict__ C,
                                               void* __restrict__ C2,
                                               int M, int N, int K,
                                               int do_silu, int c_fp32, int uv_mode) {
  __shared__ unsigned short Al[2][MTILES * 1024];   // MTILES*32 rows x 32 elems
  __shared__ unsigned short Bl[2][4096];            // 128 rows x 32 elems
  int m0 = blockIdx.y * (MTILES * 32), n0 = blockIdx.x * 128;
  int tid = threadIdx.x;
  int lane = tid & 63, w = tid >> 6;
  int rw = (w >> 1) * (MTILES * 16), cw = (w & 1) * 64;
  int q = lane >> 4, l16 = lane & 15;
  floatx4 acc[MTILES][4];
#pragma unroll
  for (int mt = 0; mt < MTILES; ++mt)
#pragma unroll
    for (int nt = 0; nt < 4; ++nt) acc[mt][nt] = (floatx4){0.f, 0.f, 0.f, 0.f};
  int grow = tid >> 2;            // row 0..63 within a 64-row segment
  int gcol = (tid & 3) * 8;       // k-offset (elems), plain lane order
  const unsigned short* A0 = A + (size_t)(m0 + grow) * K + gcol;
  const unsigned short* A1 = A0 + (size_t)64 * K;
  const unsigned short* B0 = Bt + (size_t)(n0 + grow) * K + gcol;
  const unsigned short* B1 = B0 + (size_t)64 * K;
  int woff = w * 512;             // wave-uniform LDS element base
  int nIter = K >> 5;
  // prologue: stage iter 0 into buffer 0
  async16(A0, &Al[0][woff]);
  if (MTILES == 4) async16(A1, &Al[0][2048 + woff]);
  async16(B0, &Bl[0][woff]);
  async16(B1, &Bl[0][2048 + woff]);
  int p = 0;
  for (int i = 0; i < nIter; ++i) {
    __syncthreads();   // drains vmcnt: buffer p staged; prev reads of p^1 done
    if (i + 1 < nIter) {           // prefetch i+1 into p^1, overlaps MFMA below
      int kn = (i + 1) << 5;
      async16(A0 + kn, &Al[p ^ 1][woff]);
      if (MTILES == 4) async16(A1 + kn, &Al[p ^ 1][2048 + woff]);
      async16(B0 + kn, &Bl[p ^ 1][woff]);
      async16(B1 + kn, &Bl[p ^ 1][2048 + woff]);
    }
    short8 af[MTILES], bfr[4];
#pragma unroll
    for (int i4 = 0; i4 < MTILES; ++i4)
      af[i4] = *(const short8*)(&Al[p][(rw + i4 * 16 + l16) * 32 + q * 8]);
#pragma unroll
    for (int i4 = 0; i4 < 4; ++i4)
      bfr[i4] = *(const short8*)(&Bl[p][(cw + i4 * 16 + l16) * 32 + q * 8]);
#pragma unroll
    for (int mt = 0; mt < MTILES; ++mt)
#pragma unroll
      for (int nt = 0; nt < 4; ++nt)
        acc[mt][nt] = __builtin_amdgcn_mfma_f32_16x16x32_bf16(af[mt], bfr[nt], acc[mt][nt], 0, 0, 0);
    p ^= 1;
  }
  // epilogue: D[row = q*4 + r][col = lane&15] per 16x16 tile (verified mapping)
  int isv = uv_mode && (n0 >= 2048);
  int ldc = uv_mode ? 2048 : N;
  int ncb = isv ? (n0 - 2048) : n0;
  const float* buse = isv ? bias2 : bias;
#pragma unroll
  for (int mt = 0; mt < MTILES; ++mt) {
#pragma unroll
    for (int nt = 0; nt < 4; ++nt) {
      int n = ncb + cw + nt * 16 + l16;
      float bsv = buse[n];
#pragma unroll
      for (int r = 0; r < 4; ++r) {
        int m = m0 + rw + mt * 16 + q * 4 + r;
        float val = acc[mt][nt][r] + bsv;
        if (do_silu) val = val / (1.0f + __expf(-val));
        if (isv) {
          size_t mrow = (size_t)(2048 + m + ((m >> 11) << 12));  // padded-V row
          ((unsigned short*)C2)[mrow * 2048 + n] = f2bf(val);
        } else if (c_fp32) {
          ((float*)C)[(size_t)m * ldc + n] = val;
        } else {
          ((unsigned short*)C)[(size_t)m * ldc + n] = f2bf(val);
        }
      }
    }
  }
}

// ---------------- out GEMM: KCH-templated (BK = KCH*32) --------------------
template <int MTILES, int KCH>
__global__ __launch_bounds__(256) void gemm_out(const unsigned short* __restrict__ A,
                                                const unsigned short* __restrict__ Bt,
                                                const float* __restrict__ bias,
                                                float* __restrict__ C,
                                                int M, int N, int K) {
  constexpr int AREG = MTILES * 1024;
  constexpr int BREG = 4096;
  __shared__ unsigned short Al[2][AREG * KCH];
  __shared__ unsigned short Bl[2][BREG * KCH];
  int m0 = blockIdx.y * (MTILES * 32), n0 = blockIdx.x * 128;
  int tid = threadIdx.x;
  int lane = tid & 63, w = tid >> 6;
  int rw = (w >> 1) * (MTILES * 16), cw = (w & 1) * 64;
  int q = lane >> 4, l16 = lane & 15;
  floatx4 acc[MTILES][4];
#pragma unroll
  for (int mt = 0; mt < MTILES; ++mt)
#pragma unroll
    for (int nt = 0; nt < 4; ++nt) acc[mt][nt] = (floatx4){0.f, 0.f, 0.f, 0.f};
  int grow = tid >> 2;
  int gcol = (tid & 3) * 8;
  const unsigned short* A0 = A + (size_t)(m0 + grow) * K + gcol;
  const unsigned short* A1 = A0 + (size_t)64 * K;
  const unsigned short* B0 = Bt + (size_t)(n0 + grow) * K + gcol;
  const unsigned short* B1 = B0 + (size_t)64 * K;
  int woff = w * 512;
  int nIter = K / (32 * KCH);
#pragma unroll
  for (int kc = 0; kc < KCH; ++kc) {
    async16(A0 + kc * 32, &Al[0][kc * AREG + woff]);
    if (MTILES == 4) async16(A1 + kc * 32, &Al[0][kc * AREG + 2048 + woff]);
    async16(B0 + kc * 32, &Bl[0][kc * BREG + woff]);
    async16(B1 + kc * 32, &Bl[0][kc * BREG + 2048 + woff]);
  }
  int p = 0;
  for (int i = 0; i < nIter; ++i) {
    __syncthreads();
    if (i + 1 < nIter) {
      int kn = (i + 1) * 32 * KCH;
#pragma unroll
      for (int kc = 0; kc < KCH; ++kc) {
        async16(A0 + kn + kc * 32, &Al[p ^ 1][kc * AREG + woff]);
        if (MTILES == 4) async16(A1 + kn + kc * 32, &Al[p ^ 1][kc * AREG + 2048 + woff]);
        async16(B0 + kn + kc * 32, &Bl[p ^ 1][kc * BREG + woff]);
        async16(B1 + kn + kc * 32, &Bl[p ^ 1][kc * BREG + 2048 + woff]);
      }
    }
#pragma unroll
    for (int kc = 0; kc < KCH; ++kc) {
      short8 af[MTILES], bfr[4];
#pragma unroll
      for (int i4 = 0; i4 < MTILES; ++i4)
        af[i4] = *(const short8*)(&Al[p][kc * AREG + (rw + i4 * 16 + l16) * 32 + q * 8]);
#pragma unroll
      for (int i4 = 0; i4 < 4; ++i4)
        bfr[i4] = *(const short8*)(&Bl[p][kc * BREG + (cw + i4 * 16 + l16) * 32 + q * 8]);
#pragma unroll
      for (int mt = 0; mt < MTILES; ++mt)
#pragma unroll
        for (int nt = 0; nt < 4; ++nt)
          acc[mt][nt] = __builtin_amdgcn_mfma_f32_16x16x32_bf16(af[mt], bfr[nt], acc[mt][nt], 0, 0, 0);
    }
    p ^= 1;
  }
#pragma unroll
  for (int mt = 0; mt < MTILES; ++mt) {
#pragma unroll
    for (int nt = 0; nt < 4; ++nt) {
      int n = n0 + cw + nt * 16 + l16;
      float bsv = bias[n];
#pragma unroll
      for (int r = 0; r < 4; ++r) {
        int m = m0 + rw + mt * 16 + q * 4 + r;
        C[(size_t)m * N + n] = acc[mt][nt][r] + bsv;
      }
    }
  }
}

// ---------------- chunked IIR scan (phase A) -------------------------------
// delta in REGISTERS (launch_bounds(256,1)); pair-carry: 15 VMEM loads/step.
__global__ __launch_bounds__(256, 1) void scan_chunks(const unsigned short* __restrict__ Vp,
                                                      const float* __restrict__ dp,
                                                      const float* __restrict__ dn,
                                                      unsigned short* __restrict__ ypl,
                                                      unsigned short* __restrict__ ynl,
                                                      float* __restrict__ Sy_ex,
                                                      float* __restrict__ SG_ex) {
  int z = blockIdx.z;            // dir*2 + b
  int dir = z >> 1, b = z & 1;
  int chunk = blockIdx.y;
  int c0 = blockIdx.x * 512 + threadIdx.x * 2;   // two channels per thread
  int h = c0 >> 7, d = c0 & 127;
  const float* dt = (dir ? dn : dp) + ((size_t)h * NTAP) * HD + d;
  float2 dreg[NTAP];
#pragma unroll
  for (int j = 0; j < NTAP; ++j) dreg[j] = *(const float2*)(dt + j * HD);
  const unsigned short* Vb = Vp + (size_t)b * VPROWS * D1 + c0;
  unsigned short* yl = (dir ? ynl : ypl) + (size_t)b * NSEQ * D1 + c0;
  float sy0 = 0.f, sy1 = 0.f, sg0 = 0.f, sg1 = 0.f;
  float carry0[NPAIR], carry1[NPAIR];
  if (!dir) {
    int t0 = chunk * CLEN;
    const unsigned short* Vrow = Vb + (size_t)(2048 + t0) * D1;
#pragma unroll
    for (int p = 0; p < NPAIR; ++p) {
      unsigned int pk = *(const unsigned int*)(Vrow - (ptrdiff_t)(LEADL[p] + 1) * D1);
      carry0[p] = bflo(pk); carry1[p] = bfhi(pk);
    }
    for (int i = 0; i < CLEN; ++i) {
      float F0 = 0.f, F1 = 0.f;
#pragma unroll
      for (int p = 0; p < NPAIR; ++p) {
        unsigned int pk = *(const unsigned int*)(Vrow - (ptrdiff_t)LEADL[p] * D1);
        float vl0 = bflo(pk), vl1 = bfhi(pk);
        F0 += dreg[LEADI[p]].x * vl0 + dreg[LEADI[p] + 1].x * carry0[p];
        F1 += dreg[LEADI[p]].y * vl1 + dreg[LEADI[p] + 1].y * carry1[p];
        carry0[p] = vl0; carry1[p] = vl1;
      }
      {
        unsigned int pk = *(const unsigned int*)(Vrow - (ptrdiff_t)SGL0_L * D1);
        F0 += dreg[SGL0_I].x * bflo(pk); F1 += dreg[SGL0_I].y * bfhi(pk);
      }
      {
        unsigned int pk = *(const unsigned int*)(Vrow - (ptrdiff_t)SGL1_L * D1);
        F0 += dreg[SGL1_I].x * bflo(pk); F1 += dreg[SGL1_I].y * bfhi(pk);
      }
      sg0 = GAMMA_F * sg0 + F0; sy0 = GAMMA_F * sy0 + sg0;
      sg1 = GAMMA_F * sg1 + F1; sy1 = GAMMA_F * sy1 + sg1;
      unsigned int pack = (unsigned int)f2bf(sy0) | ((unsigned int)f2bf(sy1) << 16);
      *(unsigned int*)(yl + (size_t)(t0 + i) * D1) = pack;
      Vrow += D1;
    }
  } else {
    int tstart = (NSEQ - 1) - chunk * CLEN;        // reversed time
    const unsigned short* Vrow = Vb + (size_t)(2048 + tstart) * D1;
#pragma unroll
    for (int p = 0; p < NPAIR; ++p) {
      unsigned int pk = *(const unsigned int*)(Vrow + (ptrdiff_t)(LEADL[p] + 1) * D1);
      carry0[p] = bflo(pk); carry1[p] = bfhi(pk);
    }
    for (int i = 0; i < CLEN; ++i) {
      float F0 = 0.f, F1 = 0.f;
#pragma unroll
      for (int p = 0; p < NPAIR; ++p) {
        unsigned int pk = *(const unsigned int*)(Vrow + (ptrdiff_t)LEADL[p] * D1);
        float vl0 = bflo(pk), vl1 = bfhi(pk);
        F0 += dreg[LEADI[p]].x * vl0 + dreg[LEADI[p] + 1].x * carry0[p];
        F1 += dreg[LEADI[p]].y * vl1 + dreg[LEADI[p] + 1].y * carry1[p];
        carry0[p] = vl0; carry1[p] = vl1;
      }
      {
        unsigned int pk = *(const unsigned int*)(Vrow + (ptrdiff_t)SGL0_L * D1);
        F0 += dreg[SGL0_I].x * bflo(pk); F1 += dreg[SGL0_I].y * bfhi(pk);
      }
      {
        unsigned int pk = *(const unsigned int*)(Vrow + (ptrdiff_t)SGL1_L * D1);
        F0 += dreg[SGL1_I].x * bflo(pk); F1 += dreg[SGL1_I].y * bfhi(pk);
      }
      sg0 = GAMMA_F * sg0 + F0; sy0 = GAMMA_F * sy0 + sg0;
      sg1 = GAMMA_F * sg1 + F1; sy1 = GAMMA_F * sy1 + sg1;
      unsigned int pack = (unsigned int)f2bf(sy0) | ((unsigned int)f2bf(sy1) << 16);
      *(unsigned int*)(yl + (size_t)(tstart - i) * D1) = pack;
      Vrow -= D1;
    }
  }
  size_t sidx = ((size_t)z * NCHUNK + chunk) * D1 + c0;
  Sy_ex[sidx] = sy0; Sy_ex[sidx + 1] = sy1;
  SG_ex[sidx] = sg0; SG_ex[sidx + 1] = sg1;
}

// ---------------- chunk-state scan (phase B) -------------------------------
__global__ __launch_bounds__(256) void state_scan(const float* __restrict__ Sy_ex,
                                                  const float* __restrict__ SG_ex,
                                                  float* __restrict__ Sy_in,
                                                  float* __restrict__ SG_in) {
  int idx = blockIdx.x * 256 + threadIdx.x;   // z*2048 + c, total 4*2048
  if (idx >= 4 * D1) return;
  int z = idx >> 11, c = idx & (D1 - 1);
  float ey = 0.f, eg = 0.f;
  for (int k = 0; k < NCHUNK; ++k) {
    size_t s = ((size_t)z * NCHUNK + k) * D1 + c;
    Sy_in[s] = ey; SG_in[s] = eg;
    float lex = Sy_ex[s], lgx = SG_ex[s];
    ey = lex + G_CL * (ey + (float)CLEN * eg);
    eg = lgx + G_CL * eg;
  }
}

// ---------------- combine + gate (phase C), 4 channels/thread --------------
__global__ __launch_bounds__(256) void combine_kernel(const unsigned short* __restrict__ ypl,
                                                      const unsigned short* __restrict__ ynl,
                                                      const unsigned short* __restrict__ Vp,
                                                      const float* __restrict__ Sy_in,
                                                      const float* __restrict__ SG_in,
                                                      const float* __restrict__ tz,
                                                      const unsigned short* __restrict__ U,
                                                      unsigned short* __restrict__ G) {
  int e = blockIdx.x * 256 + threadIdx.x;     // quad index over [b][t][c/4]
  int cq = e & (D1 / 4 - 1);
  int c0 = cq * 4;
  int r = e >> 9;
  int t = r & (NSEQ - 1);
  int b = r >> 11;
  int kp = t >> 4;  float dpD = (float)((t & 15) + 1);
  int tau = (NSEQ - 1) - t;
  int kn = tau >> 4; float dnD = (float)((tau & 15) + 1);
  float gp = __expf(dpD * LN_G);
  float gn = __expf(dnD * LN_G);
  size_t ix = (size_t)r * D1 + c0;
  size_t sp = ((size_t)(b) * NCHUNK + kp) * D1 + c0;          // z = b (pos)
  size_t sn = ((size_t)(2 + b) * NCHUNK + kn) * D1 + c0;      // z = 2+b (neg)
  uint2 pyl = *(const uint2*)(ypl + ix);
  uint2 pyn = *(const uint2*)(ynl + ix);
  uint2 pv  = *(const uint2*)(Vp + ((size_t)b * VPROWS + 2048 + t) * D1 + c0);
  uint2 pu  = *(const uint2*)(U + ix);
  float4 syp = *(const float4*)(Sy_in + sp);
  float4 sgp = *(const float4*)(SG_in + sp);
  float4 syn = *(const float4*)(Sy_in + sn);
  float4 sgn = *(const float4*)(SG_in + sn);
  float4 tzv = *(const float4*)(tz + c0);
  float yv[4], uv[4], vv[4];
  yv[0] = bflo(pyl.x) + gp * (syp.x + dpD * sgp.x) + bflo(pyn.x) + gn * (syn.x + dnD * sgn.x);
  yv[1] = bfhi(pyl.x) + gp * (syp.y + dpD * sgp.y) + bfhi(pyn.x) + gn * (syn.y + dnD * sgn.y);
  yv[2] = bflo(pyl.y) + gp * (syp.z + dpD * sgp.z) + bflo(pyn.y) + gn * (syn.z + dnD * sgn.z);
  yv[3] = bfhi(pyl.y) + gp * (syp.w + dpD * sgp.w) + bfhi(pyn.y) + gn * (syn.w + dnD * sgn.w);
  vv[0] = bflo(pv.x); vv[1] = bfhi(pv.x); vv[2] = bflo(pv.y); vv[3] = bfhi(pv.y);
  uv[0] = bflo(pu.x); uv[1] = bfhi(pu.x); uv[2] = bflo(pu.y); uv[3] = bfhi(pu.y);
  float tza[4] = {tzv.x, tzv.y, tzv.z, tzv.w};
  uint2 og;
  unsigned short g0 = f2bf(uv[0] * (yv[0] + tza[0] * vv[0]));
  unsigned short g1 = f2bf(uv[1] * (yv[1] + tza[1] * vv[1]));
  unsigned short g2 = f2bf(uv[2] * (yv[2] + tza[2] * vv[2]));
  unsigned short g3 = f2bf(uv[3] * (yv[3] + tza[3] * vv[3]));
  og.x = (unsigned int)g0 | ((unsigned int)g1 << 16);
  og.y = (unsigned int)g2 | ((unsigned int)g3 << 16);
  *(uint2*)(G + ix) = og;
}

// ---------------------------------------------------------------------------
extern "C" void kernel_launch(void* const* d_in, const int* in_sizes, int n_in,
                              void* d_out, int out_size, void* d_ws, size_t ws_size,
                              hipStream_t stream) {
  const float* x      = (const float*)d_in[0];
  const float* Wu     = (const float*)d_in[1];
  const float* bu     = (const float*)d_in[2];
  const float* Wv     = (const float*)d_in[3];
  const float* bv     = (const float*)d_in[4];
  const float* Wo     = (const float*)d_in[5];
  const float* bo     = (const float*)d_in[6];
  const float* a_pos  = (const float*)d_in[7];
  const float* b_pos  = (const float*)d_in[8];
  const float* a_neg  = (const float*)d_in[9];
  const float* b_neg  = (const float*)d_in[10];
  const float* t_zero = (const float*)d_in[11];
  float* out = (float*)d_out;

  char* ws = (char*)d_ws;
  unsigned short* x_bf  = (unsigned short*)ws; ws += (size_t)MROWS * DM * 2;        //  8 MB
  unsigned short* u_ws  = (unsigned short*)ws; ws += (size_t)MROWS * D1 * 2;        // 16 MB (g in-place)
  unsigned short* Vp    = (unsigned short*)ws; ws += (size_t)BB * VPROWS * D1 * 2;  // 48 MB padded V
  unsigned short* ypl   = (unsigned short*)ws; ws += (size_t)MROWS * D1 * 2;        // 16 MB
  unsigned short* ynl   = (unsigned short*)ws; ws += (size_t)MROWS * D1 * 2;        // 16 MB
  unsigned short* WoT   = (unsigned short*)ws; ws += (size_t)DM * D1 * 2;           //  4 MB (dedicated)
  float* dtp   = (float*)ws; ws += (size_t)H * NTAP * HD * 4;                       // 229 KB (fp32!)
  float* dtn   = (float*)ws; ws += (size_t)H * NTAP * HD * 4;
  float* Sy_in = (float*)ws; ws += (size_t)4 * NCHUNK * D1 * 4;                     // 4 MB each
  float* SG_in = (float*)ws; ws += (size_t)4 * NCHUNK * D1 * 4;
  // exit-state arrays alias x_bf (dead after the uv-gemm, 8 MB = exactly fits)
  float* Sy_ex = (float*)x_bf;
  float* SG_ex = (float*)x_bf + (size_t)4 * NCHUNK * D1;
  // uv weight buffer aliases ypl (disjoint lifetime, stream-ordered)
  unsigned short* WT2 = ypl;

  dim3 tb256(256);
  // prep: x->bf16 + zero V pads (one dispatch)
  prep_kernel<<<dim3((CVT4 + PAD16 + 255) / 256), tb256, 0, stream>>>(x, x_bf, Vp);
  // fused weight prep: Wo^T | Wu^T | Wv^T | kdtab (one dispatch)
  wprep_kernel<<<dim3(6176), tb256, 0, stream>>>(
      Wu, Wv, Wo, WT2, WoT, a_pos, b_pos, a_neg, b_neg, dtp, dtn);
  // fused u|v gemm: Bt = [WuT ; WvT]  (N = 4096), 128x128 tiles (R12 body)
  gemm_uv<4><<<dim3(2 * D1 / 128, MROWS / 128), tb256, 0, stream>>>(
      x_bf, WT2, bu, bv, u_ws, Vp, MROWS, 2 * D1, DM, 1, 0, 1);
  // IIR conv: chunked scans -> state scan -> combine+gate (in-place over u)
  scan_chunks<<<dim3(D1 / 512, NCHUNK, 4), tb256, 0, stream>>>(Vp, dtp, dtn, ypl, ynl, Sy_ex, SG_ex);
  state_scan<<<dim3((4 * D1 + 255) / 256), tb256, 0, stream>>>(Sy_ex, SG_ex, Sy_in, SG_in);
  combine_kernel<<<dim3((size_t)MROWS * D1 / 1024), tb256, 0, stream>>>(ypl, ynl, Vp, Sy_in, SG_in, t_zero, u_ws, u_ws);
  // out = g @ Wo + bo (fp32), 64x128 tiles, KCH=2 (BK=64, half the barriers)
  gemm_out<2, 2><<<dim3(DM / 128, MROWS / 64), tb256, 0, stream>>>(
      u_ws, WoT, bo, out, MROWS, DM, D1);
}

// Round 16
// 291.901 us; speedup vs baseline: 1.1027x; 1.0159x over previous
//
#include <hip/hip_runtime.h>
#include <hip/hip_bf16.h>
#include <stdint.h>
#include <stddef.h>

// Problem constants (fixed by the reference)
#define BB 2
#define NSEQ 2048
#define DM 1024
#define H 16
#define HD 128
#define D1 2048
#define NKI 16
#define RANKI 32
#define MROWS (BB * NSEQ)   // 4096 rows for all GEMMs
#define VPROWS 6144         // 2048 zero-pad | 2048 data | 2048 zero-pad
#define NTAP 28
#define NPAIR 13
#define NCHUNK 128
#define CLEN 16
#define GAMMA_F 0.999f
#define G_CL 0.9841201f     // 0.999^16 (chunk-length homogeneous decay)
#define LN_G (-1.00050033e-3f)

// NOTE: delta must remain fp32 everywhere [R9]. No XOR swizzle [R10/R11].
// No 32x32x16 MFMA (bank conflicts) [R13]. uv-gemm body = exact R12 codegen
// (KCH-templating it regressed VGPR 80->84, 69->99 us) [R14].
__device__ constexpr int TAPS[NTAP] = {
  1, 2, 138, 139, 274, 275, 411, 412, 547, 548, 684,
  820, 821, 956, 957, 1093, 1094, 1229, 1230, 1366,
  1502, 1503, 1638, 1639, 1775, 1776, 1911, 1912};
__device__ constexpr int LEADL[NPAIR] = {1, 138, 274, 411, 547, 820, 956, 1093, 1229, 1502, 1638, 1775, 1911};
__device__ constexpr int LEADI[NPAIR] = {0, 2, 4, 6, 8, 11, 13, 15, 17, 20, 22, 24, 26};
#define SGL0_L 684
#define SGL0_I 10
#define SGL1_L 1366
#define SGL1_I 19

typedef short short8 __attribute__((ext_vector_type(8)));
typedef float floatx4 __attribute__((ext_vector_type(4)));

__device__ __forceinline__ float bf2f(unsigned short u) {
  union { unsigned int i; float f; } v; v.i = ((unsigned int)u) << 16; return v.f;
}
__device__ __forceinline__ unsigned short f2bf(float f) {
  union { float f; unsigned int i; } v; v.f = f;
  unsigned int r = (v.i + 0x7FFFu + ((v.i >> 16) & 1u)) >> 16;
  return (unsigned short)r;
}
__device__ __forceinline__ float bflo(unsigned int p) {
  union { unsigned int i; float f; } v; v.i = p << 16; return v.f;
}
__device__ __forceinline__ float bfhi(unsigned int p) {
  union { unsigned int i; float f; } v; v.i = p & 0xffff0000u; return v.f;
}
// async 16B global->LDS DMA: lane i lands at (wave-uniform) l + i*16 bytes
__device__ __forceinline__ void async16(const unsigned short* g, unsigned short* l) {
  __builtin_amdgcn_global_load_lds(
      (const __attribute__((address_space(1))) unsigned int*)g,
      (__attribute__((address_space(3))) unsigned int*)l, 16, 0, 0);
}

// ------- prep: x fp32->bf16 convert + zero the 4 V pad regions (1 dispatch) -
#define CVT4 (MROWS * DM / 4)            // 1048576 float4->ushort4 units
#define PAD16 (4 * NSEQ * D1 / 8)        // 2097152 uint4 (8-short) pad writes
__global__ __launch_bounds__(256) void prep_kernel(const float* __restrict__ x,
                                                   unsigned short* __restrict__ x_bf,
                                                   unsigned short* __restrict__ Vp) {
  int i = blockIdx.x * 256 + threadIdx.x;
  if (i < CVT4) {
    float4 f = ((const float4*)x)[i];
    ushort4 o;
    o.x = f2bf(f.x); o.y = f2bf(f.y); o.z = f2bf(f.z); o.w = f2bf(f.w);
    ((ushort4*)x_bf)[i] = o;
  } else {
    int j = i - CVT4;
    if (j < PAD16) {
      int r = j >> 19;            // region 0..3, each 524288 uint4
      int off = j & 524287;
      const size_t bases[4] = {0, (size_t)4096 * D1, (size_t)VPROWS * D1,
                               (size_t)VPROWS * D1 + (size_t)4096 * D1};
      uint4 z; z.x = z.y = z.z = z.w = 0u;
      ((uint4*)(Vp + bases[r]))[off] = z;
    }
  }
}

// ---- K(l) = interp(kind, l) * gamma^l on an LDS copy of kind --------------
__device__ __forceinline__ float KinterpL(const float* kk, int l, int d) {
  if (l < 1) return 0.0f;   // l > 2047 never queried (max tap 1912)
  float p = (float)(l - 1) * (15.0f / 2046.0f);
  int lo = (int)p; if (lo > 15) lo = 15;
  int hi = lo + 1; if (hi > 15) hi = 15;
  float w = p - (float)lo;
  float v = kk[lo * HD + d] * (1.0f - w) + kk[hi * HD + d] * w;
  return v * __powf(GAMMA_F, (float)l);
}

// ---- fused weight prep: Wo transpose | Wu/Wv transposes | kdtab -----------
// blockIdx.x ranges: [0,2048) Wo tiles; [2048,6144) uv tiles; [6144,6176) kdtab.
__global__ __launch_bounds__(256) void wprep_kernel(const float* __restrict__ Wu,
                                                    const float* __restrict__ Wv,
                                                    const float* __restrict__ Wo,
                                                    unsigned short* __restrict__ WT2,
                                                    unsigned short* __restrict__ WoT,
                                                    const float* __restrict__ ap,
                                                    const float* __restrict__ bp,
                                                    const float* __restrict__ an,
                                                    const float* __restrict__ bn,
                                                    float* __restrict__ dtp,
                                                    float* __restrict__ dtn) {
  int blk = blockIdx.x;
  int tid = threadIdx.x;
  if (blk < 6144) {
    __shared__ unsigned short t[32][33];
    const float* in; unsigned short* out;
    int rows, cols, bx, by;
    if (blk < 2048) {           // Wo [D1][DM] -> WoT [DM][D1]
      in = Wo; out = WoT; rows = D1; cols = DM;
      bx = (blk & 31) * 32; by = (blk >> 5) * 32;
    } else {                    // Wu/Wv [DM][D1] -> WT2 [2*D1][DM]
      int local = blk - 2048;
      int z = local >> 11, l2 = local & 2047;
      in = z ? Wv : Wu; out = WT2 + (size_t)z * D1 * DM;
      rows = DM; cols = D1;
      bx = (l2 & 63) * 32; by = (l2 >> 6) * 32;
    }
    int tx = tid & 31, ty = tid >> 5;   // (32,8) flattened
#pragma unroll
    for (int j = 0; j < 32; j += 8)
      t[ty + j][tx] = f2bf(in[(size_t)(by + ty + j) * cols + bx + tx]);
    __syncthreads();
#pragma unroll
    for (int j = 0; j < 32; j += 8)
      out[(size_t)(bx + ty + j) * rows + by + tx] = t[tx][ty + j];
  } else {                      // kdtab: 32 blocks = (h, dir)
    __shared__ float kk[NKI * HD];  // 8 KB
    int e0 = blk - 6144;
    int h = e0 & 15, dir = e0 >> 4;
    const float* a = (dir ? an : ap) + h * NKI * RANKI;
    const float* b = (dir ? bn : bp) + h * RANKI * HD;
    for (int e = tid; e < NKI * HD; e += 256) {
      int k = e >> 7, d = e & 127;
      float s = 0.0f;
#pragma unroll
      for (int r = 0; r < RANKI; ++r) s += a[k * RANKI + r] * b[r * HD + d];
      kk[e] = s;
    }
    __syncthreads();
    float* dt = (dir ? dtn : dtp) + (size_t)h * NTAP * HD;
    for (int e = tid; e < NTAP * HD; e += 256) {
      int j = e >> 7, d = e & 127;
      int l = TAPS[j];
      float K0 = KinterpL(kk, l, d);
      float K1 = KinterpL(kk, l - 1, d);
      float K2 = KinterpL(kk, l - 2, d);
      dt[e] = K0 - 2.0f * GAMMA_F * K1 + (GAMMA_F * GAMMA_F) * K2;
    }
  }
}

// ---------------- uv GEMM: exact R12 body (do not touch — see note) --------
// C = silu(A @ Bt^T + bias). (MTILES*32)x128 tile, BK=32, dbuf LDS,
// global_load_lds width=16. N=4096 fused u|v; n>=2048 -> Vp (row-remapped).
template <int MTILES>
__global__ __launch_bounds__(256) void gemm_uv(const unsigned short* __restrict__ A,
                                               const unsigned short* __restrict__ Bt,
                                               const float* __restrict__ bias,
                                               const float* __restrict__ bias2,
                                               void* __restrict__ C,
                                               void* __restrict__ C2,
                                               int M, int N, int K,
                                               int do_silu, int c_fp32, int uv_mode) {
  __shared__ unsigned short Al[2][MTILES * 1024];   // MTILES*32 rows x 32 elems
  __shared__ unsigned short Bl[2][4096];            // 128 rows x 32 elems
  int m0 = blockIdx.y * (MTILES * 32), n0 = blockIdx.x * 128;
  int tid = threadIdx.x;
  int lane = tid & 63, w = tid >> 6;
  int rw = (w >> 1) * (MTILES * 16), cw = (w & 1) * 64;
  int q = lane >> 4, l16 = lane & 15;
  floatx4 acc[MTILES][4];
#pragma unroll
  for (int mt = 0; mt < MTILES; ++mt)
#pragma unroll
    for (int nt = 0; nt < 4; ++nt) acc[mt][nt] = (floatx4){0.f, 0.f, 0.f, 0.f};
  int grow = tid >> 2;            // row 0..63 within a 64-row segment
  int gcol = (tid & 3) * 8;       // k-offset (elems), plain lane order
  const unsigned short* A0 = A + (size_t)(m0 + grow) * K + gcol;
  const unsigned short* A1 = A0 + (size_t)64 * K;
  const unsigned short* B0 = Bt + (size_t)(n0 + grow) * K + gcol;
  const unsigned short* B1 = B0 + (size_t)64 * K;
  int woff = w * 512;             // wave-uniform LDS element base
  int nIter = K >> 5;
  // prologue: stage iter 0 into buffer 0
  async16(A0, &Al[0][woff]);
  if (MTILES == 4) async16(A1, &Al[0][2048 + woff]);
  async16(B0, &Bl[0][woff]);
  async16(B1, &Bl[0][2048 + woff]);
  int p = 0;
  for (int i = 0; i < nIter; ++i) {
    __syncthreads();   // drains vmcnt: buffer p staged; prev reads of p^1 done
    if (i + 1 < nIter) {           // prefetch i+1 into p^1, overlaps MFMA below
      int kn = (i + 1) << 5;
      async16(A0 + kn, &Al[p ^ 1][woff]);
      if (MTILES == 4) async16(A1 + kn, &Al[p ^ 1][2048 + woff]);
      async16(B0 + kn, &Bl[p ^ 1][woff]);
      async16(B1 + kn, &Bl[p ^ 1][2048 + woff]);
    }
    short8 af[MTILES], bfr[4];
#pragma unroll
    for (int i4 = 0; i4 < MTILES; ++i4)
      af[i4] = *(const short8*)(&Al[p][(rw + i4 * 16 + l16) * 32 + q * 8]);
#pragma unroll
    for (int i4 = 0; i4 < 4; ++i4)
      bfr[i4] = *(const short8*)(&Bl[p][(cw + i4 * 16 + l16) * 32 + q * 8]);
#pragma unroll
    for (int mt = 0; mt < MTILES; ++mt)
#pragma unroll
      for (int nt = 0; nt < 4; ++nt)
        acc[mt][nt] = __builtin_amdgcn_mfma_f32_16x16x32_bf16(af[mt], bfr[nt], acc[mt][nt], 0, 0, 0);
    p ^= 1;
  }
  // epilogue: D[row = q*4 + r][col = lane&15] per 16x16 tile (verified mapping)
  int isv = uv_mode && (n0 >= 2048);
  int ldc = uv_mode ? 2048 : N;
  int ncb = isv ? (n0 - 2048) : n0;
  const float* buse = isv ? bias2 : bias;
#pragma unroll
  for (int mt = 0; mt < MTILES; ++mt) {
#pragma unroll
    for (int nt = 0; nt < 4; ++nt) {
      int n = ncb + cw + nt * 16 + l16;
      float bsv = buse[n];
#pragma unroll
      for (int r = 0; r < 4; ++r) {
        int m = m0 + rw + mt * 16 + q * 4 + r;
        float val = acc[mt][nt][r] + bsv;
        if (do_silu) val = val / (1.0f + __expf(-val));
        if (isv) {
          size_t mrow = (size_t)(2048 + m + ((m >> 11) << 12));  // padded-V row
          ((unsigned short*)C2)[mrow * 2048 + n] = f2bf(val);
        } else if (c_fp32) {
          ((float*)C)[(size_t)m * ldc + n] = val;
        } else {
          ((unsigned short*)C)[(size_t)m * ldc + n] = f2bf(val);
        }
      }
    }
  }
}

// ---------------- out GEMM: KCH-templated (BK = KCH*32) --------------------
template <int MTILES, int KCH>
__global__ __launch_bounds__(256) void gemm_out(const unsigned short* __restrict__ A,
                                                const unsigned short* __restrict__ Bt,
                                                const float* __restrict__ bias,
                                                float* __restrict__ C,
                                                int M, int N, int K) {
  constexpr int AREG = MTILES * 1024;
  constexpr int BREG = 4096;
  __shared__ unsigned short Al[2][AREG * KCH];
  __shared__ unsigned short Bl[2][BREG * KCH];
  int m0 = blockIdx.y * (MTILES * 32), n0 = blockIdx.x * 128;
  int tid = threadIdx.x;
  int lane = tid & 63, w = tid >> 6;
  int rw = (w >> 1) * (MTILES * 16), cw = (w & 1) * 64;
  int q = lane >> 4, l16 = lane & 15;
  floatx4 acc[MTILES][4];
#pragma unroll
  for (int mt = 0; mt < MTILES; ++mt)
#pragma unroll
    for (int nt = 0; nt < 4; ++nt) acc[mt][nt] = (floatx4){0.f, 0.f, 0.f, 0.f};
  int grow = tid >> 2;
  int gcol = (tid & 3) * 8;
  const unsigned short* A0 = A + (size_t)(m0 + grow) * K + gcol;
  const unsigned short* A1 = A0 + (size_t)64 * K;
  const unsigned short* B0 = Bt + (size_t)(n0 + grow) * K + gcol;
  const unsigned short* B1 = B0 + (size_t)64 * K;
  int woff = w * 512;
  int nIter = K / (32 * KCH);
#pragma unroll
  for (int kc = 0; kc < KCH; ++kc) {
    async16(A0 + kc * 32, &Al[0][kc * AREG + woff]);
    if (MTILES == 4) async16(A1 + kc * 32, &Al[0][kc * AREG + 2048 + woff]);
    async16(B0 + kc * 32, &Bl[0][kc * BREG + woff]);
    async16(B1 + kc * 32, &Bl[0][kc * BREG + 2048 + woff]);
  }
  int p = 0;
  for (int i = 0; i < nIter; ++i) {
    __syncthreads();
    if (i + 1 < nIter) {
      int kn = (i + 1) * 32 * KCH;
#pragma unroll
      for (int kc = 0; kc < KCH; ++kc) {
        async16(A0 + kn + kc * 32, &Al[p ^ 1][kc * AREG + woff]);
        if (MTILES == 4) async16(A1 + kn + kc * 32, &Al[p ^ 1][kc * AREG + 2048 + woff]);
        async16(B0 + kn + kc * 32, &Bl[p ^ 1][kc * BREG + woff]);
        async16(B1 + kn + kc * 32, &Bl[p ^ 1][kc * BREG + 2048 + woff]);
      }
    }
#pragma unroll
    for (int kc = 0; kc < KCH; ++kc) {
      short8 af[MTILES], bfr[4];
#pragma unroll
      for (int i4 = 0; i4 < MTILES; ++i4)
        af[i4] = *(const short8*)(&Al[p][kc * AREG + (rw + i4 * 16 + l16) * 32 + q * 8]);
#pragma unroll
      for (int i4 = 0; i4 < 4; ++i4)
        bfr[i4] = *(const short8*)(&Bl[p][kc * BREG + (cw + i4 * 16 + l16) * 32 + q * 8]);
#pragma unroll
      for (int mt = 0; mt < MTILES; ++mt)
#pragma unroll
        for (int nt = 0; nt < 4; ++nt)
          acc[mt][nt] = __builtin_amdgcn_mfma_f32_16x16x32_bf16(af[mt], bfr[nt], acc[mt][nt], 0, 0, 0);
    }
    p ^= 1;
  }
#pragma unroll
  for (int mt = 0; mt < MTILES; ++mt) {
#pragma unroll
    for (int nt = 0; nt < 4; ++nt) {
      int n = n0 + cw + nt * 16 + l16;
      float bsv = bias[n];
#pragma unroll
      for (int r = 0; r < 4; ++r) {
        int m = m0 + rw + mt * 16 + q * 4 + r;
        C[(size_t)m * N + n] = acc[mt][nt][r] + bsv;
      }
    }
  }
}

// ---------------- chunked IIR scan (phase A) -------------------------------
// delta in REGISTERS (launch_bounds(256,1)); pair-carry: 15 VMEM loads/step.
__global__ __launch_bounds__(256, 1) void scan_chunks(const unsigned short* __restrict__ Vp,
                                                      const float* __restrict__ dp,
                                                      const float* __restrict__ dn,
                                                      unsigned short* __restrict__ ypl,
                                                      unsigned short* __restrict__ ynl,
                                                      float* __restrict__ Sy_ex,
                                                      float* __restrict__ SG_ex) {
  int z = blockIdx.z;            // dir*2 + b
  int dir = z >> 1, b = z & 1;
  int chunk = blockIdx.y;
  int c0 = blockIdx.x * 512 + threadIdx.x * 2;   // two channels per thread
  int h = c0 >> 7, d = c0 & 127;
  const float* dt = (dir ? dn : dp) + ((size_t)h * NTAP) * HD + d;
  float2 dreg[NTAP];
#pragma unroll
  for (int j = 0; j < NTAP; ++j) dreg[j] = *(const float2*)(dt + j * HD);
  const unsigned short* Vb = Vp + (size_t)b * VPROWS * D1 + c0;
  unsigned short* yl = (dir ? ynl : ypl) + (size_t)b * NSEQ * D1 + c0;
  float sy0 = 0.f, sy1 = 0.f, sg0 = 0.f, sg1 = 0.f;
  float carry0[NPAIR], carry1[NPAIR];
  if (!dir) {
    int t0 = chunk * CLEN;
    const unsigned short* Vrow = Vb + (size_t)(2048 + t0) * D1;
#pragma unroll
    for (int p = 0; p < NPAIR; ++p) {
      unsigned int pk = *(const unsigned int*)(Vrow - (ptrdiff_t)(LEADL[p] + 1) * D1);
      carry0[p] = bflo(pk); carry1[p] = bfhi(pk);
    }
    for (int i = 0; i < CLEN; ++i) {
      float F0 = 0.f, F1 = 0.f;
#pragma unroll
      for (int p = 0; p < NPAIR; ++p) {
        unsigned int pk = *(const unsigned int*)(Vrow - (ptrdiff_t)LEADL[p] * D1);
        float vl0 = bflo(pk), vl1 = bfhi(pk);
        F0 += dreg[LEADI[p]].x * vl0 + dreg[LEADI[p] + 1].x * carry0[p];
        F1 += dreg[LEADI[p]].y * vl1 + dreg[LEADI[p] + 1].y * carry1[p];
        carry0[p] = vl0; carry1[p] = vl1;
      }
      {
        unsigned int pk = *(const unsigned int*)(Vrow - (ptrdiff_t)SGL0_L * D1);
        F0 += dreg[SGL0_I].x * bflo(pk); F1 += dreg[SGL0_I].y * bfhi(pk);
      }
      {
        unsigned int pk = *(const unsigned int*)(Vrow - (ptrdiff_t)SGL1_L * D1);
        F0 += dreg[SGL1_I].x * bflo(pk); F1 += dreg[SGL1_I].y * bfhi(pk);
      }
      sg0 = GAMMA_F * sg0 + F0; sy0 = GAMMA_F * sy0 + sg0;
      sg1 = GAMMA_F * sg1 + F1; sy1 = GAMMA_F * sy1 + sg1;
      unsigned int pack = (unsigned int)f2bf(sy0) | ((unsigned int)f2bf(sy1) << 16);
      *(unsigned int*)(yl + (size_t)(t0 + i) * D1) = pack;
      Vrow += D1;
    }
  } else {
    int tstart = (NSEQ - 1) - chunk * CLEN;        // reversed time
    const unsigned short* Vrow = Vb + (size_t)(2048 + tstart) * D1;
#pragma unroll
    for (int p = 0; p < NPAIR; ++p) {
      unsigned int pk = *(const unsigned int*)(Vrow + (ptrdiff_t)(LEADL[p] + 1) * D1);
      carry0[p] = bflo(pk); carry1[p] = bfhi(pk);
    }
    for (int i = 0; i < CLEN; ++i) {
      float F0 = 0.f, F1 = 0.f;
#pragma unroll
      for (int p = 0; p < NPAIR; ++p) {
        unsigned int pk = *(const unsigned int*)(Vrow + (ptrdiff_t)LEADL[p] * D1);
        float vl0 = bflo(pk), vl1 = bfhi(pk);
        F0 += dreg[LEADI[p]].x * vl0 + dreg[LEADI[p] + 1].x * carry0[p];
        F1 += dreg[LEADI[p]].y * vl1 + dreg[LEADI[p] + 1].y * carry1[p];
        carry0[p] = vl0; carry1[p] = vl1;
      }
      {
        unsigned int pk = *(const unsigned int*)(Vrow + (ptrdiff_t)SGL0_L * D1);
        F0 += dreg[SGL0_I].x * bflo(pk); F1 += dreg[SGL0_I].y * bfhi(pk);
      }
      {
        unsigned int pk = *(const unsigned int*)(Vrow + (ptrdiff_t)SGL1_L * D1);
        F0 += dreg[SGL1_I].x * bflo(pk); F1 += dreg[SGL1_I].y * bfhi(pk);
      }
      sg0 = GAMMA_F * sg0 + F0; sy0 = GAMMA_F * sy0 + sg0;
      sg1 = GAMMA_F * sg1 + F1; sy1 = GAMMA_F * sy1 + sg1;
      unsigned int pack = (unsigned int)f2bf(sy0) | ((unsigned int)f2bf(sy1) << 16);
      *(unsigned int*)(yl + (size_t)(tstart - i) * D1) = pack;
      Vrow -= D1;
    }
  }
  size_t sidx = ((size_t)z * NCHUNK + chunk) * D1 + c0;
  Sy_ex[sidx] = sy0; Sy_ex[sidx + 1] = sy1;
  SG_ex[sidx] = sg0; SG_ex[sidx + 1] = sg1;
}

// ---------------- chunk-state scan (phase B) -------------------------------
__global__ __launch_bounds__(256) void state_scan(const float* __restrict__ Sy_ex,
                                                  const float* __restrict__ SG_ex,
                                                  float* __restrict__ Sy_in,
                                                  float* __restrict__ SG_in) {
  int idx = blockIdx.x * 256 + threadIdx.x;   // z*2048 + c, total 4*2048
  if (idx >= 4 * D1) return;
  int z = idx >> 11, c = idx & (D1 - 1);
  float ey = 0.f, eg = 0.f;
  for (int k = 0; k < NCHUNK; ++k) {
    size_t s = ((size_t)z * NCHUNK + k) * D1 + c;
    Sy_in[s] = ey; SG_in[s] = eg;
    float lex = Sy_ex[s], lgx = SG_ex[s];
    ey = lex + G_CL * (ey + (float)CLEN * eg);
    eg = lgx + G_CL * eg;
  }
}

// ---------------- combine + gate (phase C), 4 channels/thread --------------
__global__ __launch_bounds__(256) void combine_kernel(const unsigned short* __restrict__ ypl,
                                                      const unsigned short* __restrict__ ynl,
                                                      const unsigned short* __restrict__ Vp,
                                                      const float* __restrict__ Sy_in,
                                                      const float* __restrict__ SG_in,
                                                      const float* __restrict__ tz,
                                                      const unsigned short* __restrict__ U,
                                                      unsigned short* __restrict__ G) {
  int e = blockIdx.x * 256 + threadIdx.x;     // quad index over [b][t][c/4]
  int cq = e & (D1 / 4 - 1);
  int c0 = cq * 4;
  int r = e >> 9;
  int t = r & (NSEQ - 1);
  int b = r >> 11;
  int kp = t >> 4;  float dpD = (float)((t & 15) + 1);
  int tau = (NSEQ - 1) - t;
  int kn = tau >> 4; float dnD = (float)((tau & 15) + 1);
  float gp = __expf(dpD * LN_G);
  float gn = __expf(dnD * LN_G);
  size_t ix = (size_t)r * D1 + c0;
  size_t sp = ((size_t)(b) * NCHUNK + kp) * D1 + c0;          // z = b (pos)
  size_t sn = ((size_t)(2 + b) * NCHUNK + kn) * D1 + c0;      // z = 2+b (neg)
  uint2 pyl = *(const uint2*)(ypl + ix);
  uint2 pyn = *(const uint2*)(ynl + ix);
  uint2 pv  = *(const uint2*)(Vp + ((size_t)b * VPROWS + 2048 + t) * D1 + c0);
  uint2 pu  = *(const uint2*)(U + ix);
  float4 syp = *(const float4*)(Sy_in + sp);
  float4 sgp = *(const float4*)(SG_in + sp);
  float4 syn = *(const float4*)(Sy_in + sn);
  float4 sgn = *(const float4*)(SG_in + sn);
  float4 tzv = *(const float4*)(tz + c0);
  float yv[4], uv[4], vv[4];
  yv[0] = bflo(pyl.x) + gp * (syp.x + dpD * sgp.x) + bflo(pyn.x) + gn * (syn.x + dnD * sgn.x);
  yv[1] = bfhi(pyl.x) + gp * (syp.y + dpD * sgp.y) + bfhi(pyn.x) + gn * (syn.y + dnD * sgn.y);
  yv[2] = bflo(pyl.y) + gp * (syp.z + dpD * sgp.z) + bflo(pyn.y) + gn * (syn.z + dnD * sgn.z);
  yv[3] = bfhi(pyl.y) + gp * (syp.w + dpD * sgp.w) + bfhi(pyn.y) + gn * (syn.w + dnD * sgn.w);
  vv[0] = bflo(pv.x); vv[1] = bfhi(pv.x); vv[2] = bflo(pv.y); vv[3] = bfhi(pv.y);
  uv[0] = bflo(pu.x); uv[1] = bfhi(pu.x); uv[2] = bflo(pu.y); uv[3] = bfhi(pu.y);
  float tza[4] = {tzv.x, tzv.y, tzv.z, tzv.w};
  uint2 og;
  unsigned short g0 = f2bf(uv[0] * (yv[0] + tza[0] * vv[0]));
  unsigned short g1 = f2bf(uv[1] * (yv[1] + tza[1] * vv[1]));
  unsigned short g2 = f2bf(uv[2] * (yv[2] + tza[2] * vv[2]));
  unsigned short g3 = f2bf(uv[3] * (yv[3] + tza[3] * vv[3]));
  og.x = (unsigned int)g0 | ((unsigned int)g1 << 16);
  og.y = (unsigned int)g2 | ((unsigned int)g3 << 16);
  *(uint2*)(G + ix) = og;
}

// ---------------------------------------------------------------------------
extern "C" void kernel_launch(void* const* d_in, const int* in_sizes, int n_in,
                              void* d_out, int out_size, void* d_ws, size_t ws_size,
                              hipStream_t stream) {
  const float* x      = (const float*)d_in[0];
  const float* Wu     = (const float*)d_in[1];
  const float* bu     = (const float*)d_in[2];
  const float* Wv     = (const float*)d_in[3];
  const float* bv     = (const float*)d_in[4];
  const float* Wo     = (const float*)d_in[5];
  const float* bo     = (const float*)d_in[6];
  const float* a_pos  = (const float*)d_in[7];
  const float* b_pos  = (const float*)d_in[8];
  const float* a_neg  = (const float*)d_in[9];
  const float* b_neg  = (const float*)d_in[10];
  const float* t_zero = (const float*)d_in[11];
  float* out = (float*)d_out;

  char* ws = (char*)d_ws;
  unsigned short* x_bf  = (unsigned short*)ws; ws += (size_t)MROWS * DM * 2;        //  8 MB
  unsigned short* u_ws  = (unsigned short*)ws; ws += (size_t)MROWS * D1 * 2;        // 16 MB (g in-place)
  unsigned short* Vp    = (unsigned short*)ws; ws += (size_t)BB * VPROWS * D1 * 2;  // 48 MB padded V
  unsigned short* ypl   = (unsigned short*)ws; ws += (size_t)MROWS * D1 * 2;        // 16 MB
  unsigned short* ynl   = (unsigned short*)ws; ws += (size_t)MROWS * D1 * 2;        // 16 MB
  unsigned short* WoT   = (unsigned short*)ws; ws += (size_t)DM * D1 * 2;           //  4 MB (dedicated)
  float* dtp   = (float*)ws; ws += (size_t)H * NTAP * HD * 4;                       // 229 KB (fp32!)
  float* dtn   = (float*)ws; ws += (size_t)H * NTAP * HD * 4;
  float* Sy_in = (float*)ws; ws += (size_t)4 * NCHUNK * D1 * 4;                     // 4 MB each
  float* SG_in = (float*)ws; ws += (size_t)4 * NCHUNK * D1 * 4;
  // exit-state arrays alias x_bf (dead after the uv-gemm, 8 MB = exactly fits)
  float* Sy_ex = (float*)x_bf;
  float* SG_ex = (float*)x_bf + (size_t)4 * NCHUNK * D1;
  // uv weight buffer aliases ypl (disjoint lifetime, stream-ordered)
  unsigned short* WT2 = ypl;

  dim3 tb256(256);
  // prep: x->bf16 + zero V pads (one dispatch)
  prep_kernel<<<dim3((CVT4 + PAD16 + 255) / 256), tb256, 0, stream>>>(x, x_bf, Vp);
  // fused weight prep: Wo^T | Wu^T | Wv^T | kdtab (one dispatch)
  wprep_kernel<<<dim3(6176), tb256, 0, stream>>>(
      Wu, Wv, Wo, WT2, WoT, a_pos, b_pos, a_neg, b_neg, dtp, dtn);
  // fused u|v gemm: Bt = [WuT ; WvT]  (N = 4096), 64x128 tiles -> 2048 blocks
  gemm_uv<2><<<dim3(2 * D1 / 128, MROWS / 64), tb256, 0, stream>>>(
      x_bf, WT2, bu, bv, u_ws, Vp, MROWS, 2 * D1, DM, 1, 0, 1);
  // IIR conv: chunked scans -> state scan -> combine+gate (in-place over u)
  scan_chunks<<<dim3(D1 / 512, NCHUNK, 4), tb256, 0, stream>>>(Vp, dtp, dtn, ypl, ynl, Sy_ex, SG_ex);
  state_scan<<<dim3((4 * D1 + 255) / 256), tb256, 0, stream>>>(Sy_ex, SG_ex, Sy_in, SG_in);
  combine_kernel<<<dim3((size_t)MROWS * D1 / 1024), tb256, 0, stream>>>(ypl, ynl, Vp, Sy_in, SG_in, t_zero, u_ws, u_ws);
  // out = g @ Wo + bo (fp32), 64x128 tiles, KCH=2 (BK=64, half the barriers)
  gemm_out<2, 2><<<dim3(DM / 128, MROWS / 64), tb256, 0, stream>>>(
      u_ws, WoT, bo, out, MROWS, DM, D1);
}